// Round 7
// baseline (555.123 us; speedup 1.0000x reference)
//
#include <hip/hip_runtime.h>

typedef __bf16 bf16x8 __attribute__((ext_vector_type(8)));
typedef float floatx4 __attribute__((ext_vector_type(4)));

#define MFMA(a, b, c) __builtin_amdgcn_mfma_f32_16x16x32_bf16((a), (b), (c), 0, 0, 0)

__device__ __forceinline__ float bf2f(ushort u) {
    union { unsigned int i; float f; } v; v.i = ((unsigned int)u) << 16; return v.f;
}
__device__ __forceinline__ ushort f2bf(float f) {
    union { float f; unsigned int i; } v; v.f = f;
    unsigned int r = v.i + 0x7fffu + ((v.i >> 16) & 1u);
    return (ushort)(r >> 16);
}
__device__ __forceinline__ bf16x8 ldb8(const ushort* p) { return *(const bf16x8*)p; }

// ---------------------------------------------------------------- fp32 -> bf16 transpose
__global__ __launch_bounds__(256) void transpose_f32_bf16(
    const float* __restrict__ in, ushort* __restrict__ out, int R, int C) {
    __shared__ ushort tile[32][33];
    const int c0 = blockIdx.x * 32, r0 = blockIdx.y * 32;
    const int tx = threadIdx.x, ty = threadIdx.y;
    #pragma unroll
    for (int i = 0; i < 32; i += 8) {
        int r = r0 + ty + i, c = c0 + tx;
        if (r < R && c < C) tile[ty + i][tx] = f2bf(in[(long)r * C + c]);
    }
    __syncthreads();
    #pragma unroll
    for (int i = 0; i < 32; i += 8) {
        int r = c0 + ty + i, c = r0 + tx;   // out is C x R
        if (r < C && c < R) out[(long)r * R + c] = tile[tx][ty + i];
    }
}

// ---------------------------------------------------------------- fp32 -> bf16 elementwise (n % 4 == 0)
__global__ __launch_bounds__(256) void cvt_f32_bf16(
    const float* __restrict__ in, ushort* __restrict__ out, long n) {
    const long i = ((long)blockIdx.x * 256 + threadIdx.x) * 4;
    if (i >= n) return;
    float4 v = *(const float4*)(in + i);
    ushort4 o;
    o.x = f2bf(v.x); o.y = f2bf(v.y); o.z = f2bf(v.z); o.w = f2bf(v.w);
    *(ushort4*)(out + i) = o;
}

// ---------------------------------------------------------------- trig table: freqs -> (cos, sin)
__global__ __launch_bounds__(256) void trigtab(
    const float* __restrict__ freqs, float2* __restrict__ trig) {
    const int idx = blockIdx.x * 256 + threadIdx.x;   // 2048*32 = 65536
    float th = freqs[idx];
    trig[idx] = make_float2(cosf(th), sinf(th));
}

// ---------------------------------------------------------------- GEMM 128-tile, global_load_lds (m97-class)
__global__ __launch_bounds__(256, 3) void gemm_bt128(
    const ushort* __restrict__ A, const ushort* __restrict__ Bt,
    void* __restrict__ C, int K, int lda, int ldb, int ldc,
    long aZ, long bZ, long cZ, int c_f32) {
    __shared__ __align__(16) ushort As[128 * 64];
    __shared__ __align__(16) ushort Bs[128 * 64];
    const int z = blockIdx.z;
    const ushort* Ab = A + (long)z * aZ;
    const ushort* Bb = Bt + (long)z * bZ;
    const long m0 = (long)blockIdx.y * 128;
    const long n0 = (long)blockIdx.x * 128;
    const int tid = threadIdx.x;
    const int lane = tid & 63, w = tid >> 6;
    const int wm = (w >> 1) * 64, wn = (w & 1) * 64;
    const int lrow = lane & 15, quad = lane >> 4;

    floatx4 acc[4][4] = {};

    for (int k0 = 0; k0 < K; k0 += 64) {
        __syncthreads();
        #pragma unroll
        for (int t = 0; t < 4; ++t) {
            const int c = t * 256 + tid;
            const int r = c >> 3, kc = (c & 7) * 8;
            __builtin_amdgcn_global_load_lds(
                (const __attribute__((address_space(1))) unsigned int*)(Ab + (m0 + r) * lda + k0 + kc),
                (__attribute__((address_space(3))) unsigned int*)(As + (long)c * 8), 16, 0, 0);
            __builtin_amdgcn_global_load_lds(
                (const __attribute__((address_space(1))) unsigned int*)(Bb + (n0 + r) * ldb + k0 + kc),
                (__attribute__((address_space(3))) unsigned int*)(Bs + (long)c * 8), 16, 0, 0);
        }
        __syncthreads();
        #pragma unroll
        for (int kk = 0; kk < 64; kk += 32) {
            bf16x8 af[4], bv[4];
            #pragma unroll
            for (int i = 0; i < 4; ++i) {
                af[i] = ldb8(&As[(wm + i * 16 + lrow) * 64 + kk + quad * 8]);
                bv[i] = ldb8(&Bs[(wn + i * 16 + lrow) * 64 + kk + quad * 8]);
            }
            #pragma unroll
            for (int i = 0; i < 4; ++i)
                #pragma unroll
                for (int j = 0; j < 4; ++j)
                    acc[i][j] = MFMA(af[i], bv[j], acc[i][j]);
        }
    }
    if (c_f32) {
        float* Cb = (float*)C + (long)z * cZ;
        #pragma unroll
        for (int mt = 0; mt < 4; ++mt)
            #pragma unroll
            for (int nt = 0; nt < 4; ++nt)
                #pragma unroll
                for (int r = 0; r < 4; ++r)
                    Cb[(m0 + wm + mt * 16 + quad * 4 + r) * ldc + n0 + wn + nt * 16 + lrow] = acc[mt][nt][r];
    } else {
        ushort* Cb = (ushort*)C + (long)z * cZ;
        #pragma unroll
        for (int mt = 0; mt < 4; ++mt)
            #pragma unroll
            for (int nt = 0; nt < 4; ++nt)
                #pragma unroll
                for (int r = 0; r < 4; ++r)
                    Cb[(m0 + wm + mt * 16 + quad * 4 + r) * ldc + n0 + wn + nt * 16 + lrow] = f2bf(acc[mt][nt][r]);
    }
}

// ---------------------------------------------------------------- RMSNorm over cols [0,1536) of 2176-stride rows (in-place)
__global__ __launch_bounds__(256) void rms1536(
    ushort* qk, const float* __restrict__ w) {
    const int row = blockIdx.x, t = threadIdx.x;
    const int lane = t & 63, wv = t >> 6;
    ushort* ip = qk + (long)row * 2176;
    float v[6]; float ss = 0.f;
    #pragma unroll
    for (int i = 0; i < 6; ++i) { v[i] = bf2f(ip[i * 256 + t]); ss += v[i] * v[i]; }
    #pragma unroll
    for (int off = 32; off > 0; off >>= 1) ss += __shfl_xor(ss, off);
    __shared__ float red[4];
    if (lane == 0) red[wv] = ss;
    __syncthreads();
    const float tot = red[0] + red[1] + red[2] + red[3];
    const float sc = rsqrtf(tot * (1.f / 1536.f) + 1e-6f);
    #pragma unroll
    for (int i = 0; i < 6; ++i) ip[i * 256 + t] = f2bf(v[i] * sc * w[i * 256 + t]);
}

// ---------------------------------------------------------------- q RoPE (table-driven)
__global__ __launch_bounds__(256) void qrope(
    const ushort* __restrict__ q, const float2* __restrict__ trig,
    ushort* __restrict__ qpe) {
    const int tok = blockIdx.x;
    const int s = tok & 2047;
    const int t = threadIdx.x;
    #pragma unroll
    for (int p = 0; p < 2; ++p) {
        const int idx = p * 256 + t;
        const int h = idx >> 5, i = idx & 31;
        const long base = (long)tok * 3072 + h * 192 + 128 + 2 * i;
        float x0 = bf2f(q[base]), x1 = bf2f(q[base + 1]);
        float2 cs = trig[s * 32 + i];
        const long ob = (long)tok * 1024 + h * 64 + 2 * i;
        qpe[ob]     = f2bf(x0 * cs.x - x1 * cs.y);
        qpe[ob + 1] = f2bf(x0 * cs.y + x1 * cs.x);
    }
}

// ---------------------------------------------------------------- kv prep: rmsnorm latent + k rope, from qk_comb cols [1536,2112)
__global__ __launch_bounds__(256) void kvprep(
    const ushort* __restrict__ qk, const float* __restrict__ w,
    const float2* __restrict__ trig, ushort* __restrict__ kvc,
    ushort* __restrict__ kpe) {
    const int tok = blockIdx.x;
    const int s = tok & 2047;
    const int t = threadIdx.x;
    const int lane = t & 63, wv = t >> 6;
    const ushort* in2 = qk + (long)tok * 2176 + 1536;
    const float v0 = bf2f(in2[t]);
    const float v1 = bf2f(in2[256 + t]);
    float ss = v0 * v0 + v1 * v1;
    #pragma unroll
    for (int off = 32; off > 0; off >>= 1) ss += __shfl_xor(ss, off);
    __shared__ float red[4];
    if (lane == 0) red[wv] = ss;
    __syncthreads();
    const float tot = red[0] + red[1] + red[2] + red[3];
    const float sc = rsqrtf(tot * (1.f / 512.f) + 1e-6f);
    kvc[(long)tok * 512 + t] = f2bf(v0 * sc * w[t]);
    kvc[(long)tok * 512 + 256 + t] = f2bf(v1 * sc * w[256 + t]);
    if (t < 32) {
        float x0 = bf2f(in2[512 + 2 * t]);
        float x1 = bf2f(in2[512 + 2 * t + 1]);
        float2 cs = trig[s * 32 + t];
        kpe[(long)tok * 64 + 2 * t]     = f2bf(x0 * cs.x - x1 * cs.y);
        kpe[(long)tok * 64 + 2 * t + 1] = f2bf(x0 * cs.y + x1 * cs.x);
    }
}

// ---------------------------------------------------------------- flash attention, non-absorbed (per-head MHA)
// Round-3 verified structure (110 us) + T14 async-STAGE split: next K-tile's global
// loads ISSUE right after barrier A (hide under QK+softmax), LDS WRITE after barrier B
// (all Ks reads done; PV touches only P/vf). Iter-0 stage synchronous.
// D_QK = 192 (128 nope + 64 rope in Ks), D_V = 128. Q-tile 64, KV-tile 128.
// Grid (16,16,2); block handles q-tiles {qx, 31-qx} -> 17 kv-iters (perfect balance).
// XCD remap keeps each (b,h) group on one XCD (kn+vT slice L2-resident).
// Causal mask evaluated only on the diagonal iteration (uniform branch).
__global__ __launch_bounds__(256, 2) void mha_attn(
    const ushort* __restrict__ q,      // (4096,3072): per-head 192, [0,128) nope
    const ushort* __restrict__ qpe,    // (4096,16,64) roped
    const ushort* __restrict__ kn,     // (2,2048,2048): k_nope, col h*128+d
    const ushort* __restrict__ kpe,    // (4096,64) roped, shared across heads
    const ushort* __restrict__ vT,     // (2,16,128,2048)
    ushort* __restrict__ o2) {         // (4096,2048): col h*128+d
    __shared__ __align__(16) ushort Ks[128][200];   // cols 0-127 nope, 128-191 rope
    __shared__ __align__(16) ushort P[64][136];     // cols 128-129 alpha(f32), 132-133 l(f32)
    // ---- XCD-aware bijective remap of (qx, h, b) ----
    const int fid = blockIdx.x + (blockIdx.y << 4) + (blockIdx.z << 8);  // 0..511
    const int xcd = fid & 7, j = fid >> 3;          // 64 blocks per XCD chunk
    const int g = xcd * 4 + (j >> 4);               // (b,h) group 0..31
    const int qx = j & 15, h = g & 15, b = g >> 4;
    const int tid = threadIdx.x, lane = tid & 63, w = tid >> 6;
    const int lrow = lane & 15, quad = lane >> 4;
    const long bb = (long)b * 2048;
    const float scale = 0.07216878364870323f * 1.4426950408889634f;  // 192^-0.5 * log2(e)
    const int rn = tid >> 4, cn = (tid & 15) * 8;   // nope staging: 16 lanes/row (256B rows)
    const int rr = tid >> 3, cr = (tid & 7) * 8;    // rope staging: 8 lanes/row (128B rows)

    for (int half = 0; half < 2; ++half) {
        const int qt = half ? (31 - qx) : qx;
        const int qrow = qt * 64;
        const long tokb = bb + qrow;

        bf16x8 qa[6];
        {
            const ushort* qp_ = q + (tokb + w * 16 + lrow) * 3072 + h * 192 + quad * 8;
            #pragma unroll
            for (int ks = 0; ks < 4; ++ks) qa[ks] = ldb8(qp_ + ks * 32);
            const ushort* qq = qpe + (tokb + w * 16 + lrow) * 1024 + h * 64 + quad * 8;
            qa[4] = ldb8(qq); qa[5] = ldb8(qq + 32);
        }

        floatx4 oacc[4][2] = {};     // [m-frag][v-frag]; wave owns v-dims [w*32, w*32+32)
        float m_i[4], l_i[4];
        #pragma unroll
        for (int r = 0; r < 4; ++r) { m_i[r] = -1e30f; l_i[r] = 0.f; }

        const int niter = qt / 2 + 1;

        // ---- synchronous stage of K-tile 0 ----
        {
            const ushort* src = kn + (bb + rn) * 2048 + h * 128 + cn;
            #pragma unroll
            for (int j2 = 0; j2 < 8; ++j2)
                *(uint4*)&Ks[j2 * 16 + rn][cn] = *(const uint4*)(src + (long)j2 * 16 * 2048);
            const ushort* srp = kpe + (bb + rr) * 64 + cr;
            #pragma unroll
            for (int j2 = 0; j2 < 4; ++j2)
                *(uint4*)&Ks[j2 * 32 + rr][128 + cr] = *(const uint4*)(srp + (long)j2 * 32 * 64);
        }

        for (int t = 0; t < niter; ++t) {
            const int kv0 = t * 128;
            __syncthreads();  // A: Ks(t) visible; prev-iter P reads done

            // ---- T14 issue-early: next K-tile global -> regs (overlaps QK+softmax) ----
            uint4 knx[8], kpx[4];
            const bool pf = (t + 1 < niter);
            if (pf) {
                const int kv1 = kv0 + 128;
                const ushort* src = kn + (bb + kv1 + rn) * 2048 + h * 128 + cn;
                #pragma unroll
                for (int j2 = 0; j2 < 8; ++j2) knx[j2] = *(const uint4*)(src + (long)j2 * 16 * 2048);
                const ushort* srp = kpe + (bb + kv1 + rr) * 64 + cr;
                #pragma unroll
                for (int j2 = 0; j2 < 4; ++j2) kpx[j2] = *(const uint4*)(srp + (long)j2 * 32 * 64);
            }

            // ---- prefetch V b-frags (L2-resident after remap) ----
            bf16x8 vf[2][4];
            {
                const ushort* vb = vT + ((long)(b * 16 + h)) * 262144 + (long)(w * 32 + lrow) * 2048 + kv0 + quad * 8;
                #pragma unroll
                for (int nf = 0; nf < 2; ++nf)
                    #pragma unroll
                    for (int kk = 0; kk < 4; ++kk)
                        vf[nf][kk] = ldb8(vb + (long)nf * 16 * 2048 + kk * 32);
            }

            // ---- QK^T: wave w owns q-rows [w*16, w*16+16), all 128 kv cols ----
            floatx4 sacc[8] = {};
            __builtin_amdgcn_s_setprio(1);
            #pragma unroll
            for (int f = 0; f < 8; ++f)
                #pragma unroll
                for (int ks = 0; ks < 6; ++ks)
                    sacc[f] = MFMA(qa[ks], ldb8(&Ks[f * 16 + lrow][ks * 32 + quad * 8]), sacc[f]);
            __builtin_amdgcn_s_setprio(0);

            // ---- online softmax (log2 domain) over 128 kv cols ----
            const bool diag = (t == niter - 1);
            #pragma unroll
            for (int r = 0; r < 4; ++r) {
                const int rloc = w * 16 + quad * 4 + r;
                const int row_s = qrow + rloc;
                float pv[8];
                float smax = -1e30f;
                #pragma unroll
                for (int f = 0; f < 8; ++f) {
                    pv[f] = sacc[f][r] * scale;
                    if (diag) { if (kv0 + f * 16 + lrow > row_s) pv[f] = -1e30f; }
                    smax = fmaxf(smax, pv[f]);
                }
                #pragma unroll
                for (int off = 1; off < 16; off <<= 1)
                    smax = fmaxf(smax, __shfl_xor(smax, off));
                const float mnew = fmaxf(m_i[r], smax);
                const float alpha = __builtin_amdgcn_exp2f(m_i[r] - mnew);
                float ps = 0.f;
                #pragma unroll
                for (int f = 0; f < 8; ++f) {
                    float p = __builtin_amdgcn_exp2f(pv[f] - mnew);
                    P[rloc][f * 16 + lrow] = f2bf(p);
                    ps += p;
                }
                #pragma unroll
                for (int off = 1; off < 16; off <<= 1)
                    ps += __shfl_xor(ps, off);
                l_i[r] = l_i[r] * alpha + ps;
                m_i[r] = mnew;
                if (lrow == 0) *(float*)&P[rloc][128] = alpha;
            }
            __syncthreads();  // B: P + alpha visible; all Ks(t) reads done

            // ---- T14 write-late: staged K-tile regs -> LDS (overlaps PV) ----
            if (pf) {
                #pragma unroll
                for (int j2 = 0; j2 < 8; ++j2) *(uint4*)&Ks[j2 * 16 + rn][cn] = knx[j2];
                #pragma unroll
                for (int j2 = 0; j2 < 4; ++j2) *(uint4*)&Ks[j2 * 32 + rr][128 + cr] = kpx[j2];
            }

            // ---- PV: wave w owns v-dims [w*32, +32), all 64 q-rows ----
            __builtin_amdgcn_s_setprio(1);
            #pragma unroll
            for (int mf = 0; mf < 4; ++mf) {
                float al[4];
                #pragma unroll
                for (int r = 0; r < 4; ++r) al[r] = *(const float*)&P[mf * 16 + quad * 4 + r][128];
                const int need = (al[0] != 1.f) | (al[1] != 1.f) | (al[2] != 1.f) | (al[3] != 1.f);
                if (__any(need)) {
                    #pragma unroll
                    for (int nf = 0; nf < 2; ++nf)
                        #pragma unroll
                        for (int r = 0; r < 4; ++r) oacc[mf][nf][r] *= al[r];
                }
                #pragma unroll
                for (int kk = 0; kk < 4; ++kk) {
                    bf16x8 pf2 = ldb8(&P[mf * 16 + lrow][kk * 32 + quad * 8]);
                    oacc[mf][0] = MFMA(pf2, vf[0][kk], oacc[mf][0]);
                    oacc[mf][1] = MFMA(pf2, vf[1][kk], oacc[mf][1]);
                }
            }
            __builtin_amdgcn_s_setprio(0);
        }

        // ---- epilogue ----
        #pragma unroll
        for (int r = 0; r < 4; ++r)
            if (lrow == 0) *(float*)&P[w * 16 + quad * 4 + r][132] = l_i[r];
        __syncthreads();
        #pragma unroll
        for (int mf = 0; mf < 4; ++mf) {
            float li[4];
            #pragma unroll
            for (int r = 0; r < 4; ++r) li[r] = *(const float*)&P[mf * 16 + quad * 4 + r][132];
            #pragma unroll
            for (int nf = 0; nf < 2; ++nf)
                #pragma unroll
                for (int r = 0; r < 4; ++r) {
                    long tok = tokb + mf * 16 + quad * 4 + r;
                    o2[tok * 2048 + h * 128 + w * 32 + nf * 16 + lrow] = f2bf(oacc[mf][nf][r] / li[r]);
                }
        }
        __syncthreads();  // protect P/Ks before next half
    }
}

// ---------------------------------------------------------------- launcher
extern "C" void kernel_launch(void* const* d_in, const int* in_sizes, int n_in,
                              void* d_out, int out_size, void* d_ws, size_t ws_size,
                              hipStream_t stream) {
    const float* x      = (const float*)d_in[0];
    const float* freqs  = (const float*)d_in[1];
    const float* wq_a   = (const float*)d_in[3];
    const float* qnw    = (const float*)d_in[4];
    const float* wq_b   = (const float*)d_in[5];
    const float* wkv_a  = (const float*)d_in[6];
    const float* kvnw   = (const float*)d_in[7];
    const float* wkv_b  = (const float*)d_in[8];
    const float* wo     = (const float*)d_in[9];
    float* out = (float*)d_out;
    (void)ws_size; (void)in_sizes; (void)n_in; (void)out_size;

    char* ws = (char*)d_ws;
    // lifetimes: qk_comb dies after kvprep -> o2 overlays it.
    //            xb dies after combined GEMM -> knope overlays it.
    ushort* qk_comb = (ushort*)(ws + 0);            // 4096x2176 bf16 = 17,825,792
    ushort* o2      = (ushort*)(ws + 0);            // 16,777,216 (after kvprep)
    ushort* xb      = (ushort*)(ws + 17825792);     // 16,777,216
    ushort* knope   = (ushort*)(ws + 17825792);     // 16,777,216 (after comb GEMM)
    ushort* q       = (ushort*)(ws + 34603008);     // 25,165,824
    ushort* qpe     = (ushort*)(ws + 59768832);     // 8,388,608
    ushort* kvc     = (ushort*)(ws + 68157440);     // 4,194,304
    ushort* kpe     = (ushort*)(ws + 72351744);     // 524,288
    ushort* vT      = (ushort*)(ws + 72876032);     // 16,777,216
    ushort* wcombT  = (ushort*)(ws + 89653248);     // 2176x2048 bf16 = 8,912,896
    ushort* wq_bT   = (ushort*)(ws + 98566144);     // 9,437,184
    ushort* wkv_bT  = (ushort*)(ws + 108003328);    // 4,194,304
    ushort* woT     = (ushort*)(ws + 112197632);    // 8,388,608
    float2* trig    = (float2*)(ws + 120586240);    // 524,288 -> ends 121,110,528

    dim3 tb(32, 8);
    trigtab<<<256, 256, 0, stream>>>(freqs, trig);
    // concat transposed weights: rows 0-1535 = wq_a^T, rows 1536-2111 = wkv_a^T, 2112-2175 pad
    transpose_f32_bf16<<<dim3(48, 64), tb, 0, stream>>>(wq_a, wcombT, 2048, 1536);
    transpose_f32_bf16<<<dim3(18, 64), tb, 0, stream>>>(wkv_a, wcombT + 1536L * 2048, 2048, 576);
    transpose_f32_bf16<<<dim3(96, 48), tb, 0, stream>>>(wq_b, wq_bT, 1536, 3072);
    transpose_f32_bf16<<<dim3(128, 16), tb, 0, stream>>>(wkv_b, wkv_bT, 512, 4096);
    transpose_f32_bf16<<<dim3(64, 64), tb, 0, stream>>>(wo, woT, 2048, 2048);
    cvt_f32_bf16<<<8192, 256, 0, stream>>>(x, xb, 8388608L);

    // qk_comb = x @ [wq_a | wkv_a]   (4096 x 2176, K=2048; cols 2112+ junk)
    gemm_bt128<<<dim3(17, 32, 1), 256, 0, stream>>>(xb, wcombT, qk_comb, 2048, 2048, 2048, 2176, 0, 0, 0, 0);
    // rmsnorm cols [0,1536) in place
    rms1536<<<4096, 256, 0, stream>>>(qk_comb, qnw);
    // q = qn @ wq_b               (4096 x 3072, K=1536; A stride 2176)
    gemm_bt128<<<dim3(24, 32, 1), 256, 0, stream>>>(qk_comb, wq_bT, q, 1536, 2176, 1536, 3072, 0, 0, 0, 0);
    // q_pe = rope(q[..., 128:192])
    qrope<<<4096, 256, 0, stream>>>(q, trig, qpe);
    // kvc (rmsnormed latent) / kpe  from qk_comb cols [1536,2112)
    kvprep<<<4096, 256, 0, stream>>>(qk_comb, kvnw, trig, kvc, kpe);

    // k_nope[b,s,h*128+d] = sum_c kvc[b,s,c] * wkv_b[c, h*256+d]   (z = head, both batches)
    gemm_bt128<<<dim3(1, 32, 16), 256, 0, stream>>>(kvc, wkv_bT, knope,
        512, 512, 512, 2048, 0, 131072, 128, 0);
    // vT[b,h,d,s] = sum_c wkv_b[c, h*256+128+d] * kvc[b,s,c]       (z = head)
    gemm_bt128<<<dim3(16, 1, 16), 256, 0, stream>>>(wkv_bT + 65536, kvc, vT,
        512, 512, 512, 2048, 131072, 0, 262144, 0);
    gemm_bt128<<<dim3(16, 1, 16), 256, 0, stream>>>(wkv_bT + 65536, kvc + 1048576, vT + 4194304,
        512, 512, 512, 2048, 131072, 0, 262144, 0);

    // flash attention (non-absorbed), writes per-head O directly
    mha_attn<<<dim3(16, 16, 2), 256, 0, stream>>>(q, qpe, knope, kpe, vT, o2);

    // out = o2 @ wo (fp32 output)
    gemm_bt128<<<dim3(16, 32, 1), 256, 0, stream>>>(o2, woT, out, 2048, 2048, 2048, 2048, 0, 0, 0, 1);
}

// Round 8
// 479.296 us; speedup vs baseline: 1.1582x; 1.1582x over previous
//
#include <hip/hip_runtime.h>

typedef __bf16 bf16x8 __attribute__((ext_vector_type(8)));
typedef float floatx4 __attribute__((ext_vector_type(4)));

#define MFMA(a, b, c) __builtin_amdgcn_mfma_f32_16x16x32_bf16((a), (b), (c), 0, 0, 0)

__device__ __forceinline__ float bf2f(ushort u) {
    union { unsigned int i; float f; } v; v.i = ((unsigned int)u) << 16; return v.f;
}
__device__ __forceinline__ ushort f2bf(float f) {
    union { float f; unsigned int i; } v; v.f = f;
    unsigned int r = v.i + 0x7fffu + ((v.i >> 16) & 1u);
    return (ushort)(r >> 16);
}
// native RTNE convert (v_cvt_pk_bf16_f32) — used in attention hot path
__device__ __forceinline__ ushort f2bf_n(float f) {
    union { __bf16 b; ushort u; } v; v.b = (__bf16)f; return v.u;
}
__device__ __forceinline__ bf16x8 ldb8(const ushort* p) { return *(const bf16x8*)p; }

// ---------------------------------------------------------------- fp32 -> bf16 transpose
__global__ __launch_bounds__(256) void transpose_f32_bf16(
    const float* __restrict__ in, ushort* __restrict__ out, int R, int C) {
    __shared__ ushort tile[32][33];
    const int c0 = blockIdx.x * 32, r0 = blockIdx.y * 32;
    const int tx = threadIdx.x, ty = threadIdx.y;
    #pragma unroll
    for (int i = 0; i < 32; i += 8) {
        int r = r0 + ty + i, c = c0 + tx;
        if (r < R && c < C) tile[ty + i][tx] = f2bf(in[(long)r * C + c]);
    }
    __syncthreads();
    #pragma unroll
    for (int i = 0; i < 32; i += 8) {
        int r = c0 + ty + i, c = r0 + tx;   // out is C x R
        if (r < C && c < R) out[(long)r * R + c] = tile[tx][ty + i];
    }
}

// ---------------------------------------------------------------- fp32 -> bf16 elementwise (n % 4 == 0)
__global__ __launch_bounds__(256) void cvt_f32_bf16(
    const float* __restrict__ in, ushort* __restrict__ out, long n) {
    const long i = ((long)blockIdx.x * 256 + threadIdx.x) * 4;
    if (i >= n) return;
    float4 v = *(const float4*)(in + i);
    ushort4 o;
    o.x = f2bf(v.x); o.y = f2bf(v.y); o.z = f2bf(v.z); o.w = f2bf(v.w);
    *(ushort4*)(out + i) = o;
}

// ---------------------------------------------------------------- trig table: freqs -> (cos, sin)
__global__ __launch_bounds__(256) void trigtab(
    const float* __restrict__ freqs, float2* __restrict__ trig) {
    const int idx = blockIdx.x * 256 + threadIdx.x;   // 2048*32 = 65536
    float th = freqs[idx];
    trig[idx] = make_float2(cosf(th), sinf(th));
}

// ---------------------------------------------------------------- GEMM 128-tile, global_load_lds (m97-class)
__global__ __launch_bounds__(256, 3) void gemm_bt128(
    const ushort* __restrict__ A, const ushort* __restrict__ Bt,
    void* __restrict__ C, int K, int lda, int ldb, int ldc,
    long aZ, long bZ, long cZ, int c_f32) {
    __shared__ __align__(16) ushort As[128 * 64];
    __shared__ __align__(16) ushort Bs[128 * 64];
    const int z = blockIdx.z;
    const ushort* Ab = A + (long)z * aZ;
    const ushort* Bb = Bt + (long)z * bZ;
    const long m0 = (long)blockIdx.y * 128;
    const long n0 = (long)blockIdx.x * 128;
    const int tid = threadIdx.x;
    const int lane = tid & 63, w = tid >> 6;
    const int wm = (w >> 1) * 64, wn = (w & 1) * 64;
    const int lrow = lane & 15, quad = lane >> 4;

    floatx4 acc[4][4] = {};

    for (int k0 = 0; k0 < K; k0 += 64) {
        __syncthreads();
        #pragma unroll
        for (int t = 0; t < 4; ++t) {
            const int c = t * 256 + tid;
            const int r = c >> 3, kc = (c & 7) * 8;
            __builtin_amdgcn_global_load_lds(
                (const __attribute__((address_space(1))) unsigned int*)(Ab + (m0 + r) * lda + k0 + kc),
                (__attribute__((address_space(3))) unsigned int*)(As + (long)c * 8), 16, 0, 0);
            __builtin_amdgcn_global_load_lds(
                (const __attribute__((address_space(1))) unsigned int*)(Bb + (n0 + r) * ldb + k0 + kc),
                (__attribute__((address_space(3))) unsigned int*)(Bs + (long)c * 8), 16, 0, 0);
        }
        __syncthreads();
        #pragma unroll
        for (int kk = 0; kk < 64; kk += 32) {
            bf16x8 af[4], bv[4];
            #pragma unroll
            for (int i = 0; i < 4; ++i) {
                af[i] = ldb8(&As[(wm + i * 16 + lrow) * 64 + kk + quad * 8]);
                bv[i] = ldb8(&Bs[(wn + i * 16 + lrow) * 64 + kk + quad * 8]);
            }
            #pragma unroll
            for (int i = 0; i < 4; ++i)
                #pragma unroll
                for (int j = 0; j < 4; ++j)
                    acc[i][j] = MFMA(af[i], bv[j], acc[i][j]);
        }
    }
    if (c_f32) {
        float* Cb = (float*)C + (long)z * cZ;
        #pragma unroll
        for (int mt = 0; mt < 4; ++mt)
            #pragma unroll
            for (int nt = 0; nt < 4; ++nt)
                #pragma unroll
                for (int r = 0; r < 4; ++r)
                    Cb[(m0 + wm + mt * 16 + quad * 4 + r) * ldc + n0 + wn + nt * 16 + lrow] = acc[mt][nt][r];
    } else {
        ushort* Cb = (ushort*)C + (long)z * cZ;
        #pragma unroll
        for (int mt = 0; mt < 4; ++mt)
            #pragma unroll
            for (int nt = 0; nt < 4; ++nt)
                #pragma unroll
                for (int r = 0; r < 4; ++r)
                    Cb[(m0 + wm + mt * 16 + quad * 4 + r) * ldc + n0 + wn + nt * 16 + lrow] = f2bf(acc[mt][nt][r]);
    }
}

// ---------------------------------------------------------------- RMSNorm over cols [0,1536) of 2176-stride rows (in-place)
__global__ __launch_bounds__(256) void rms1536(
    ushort* qk, const float* __restrict__ w) {
    const int row = blockIdx.x, t = threadIdx.x;
    const int lane = t & 63, wv = t >> 6;
    ushort* ip = qk + (long)row * 2176;
    float v[6]; float ss = 0.f;
    #pragma unroll
    for (int i = 0; i < 6; ++i) { v[i] = bf2f(ip[i * 256 + t]); ss += v[i] * v[i]; }
    #pragma unroll
    for (int off = 32; off > 0; off >>= 1) ss += __shfl_xor(ss, off);
    __shared__ float red[4];
    if (lane == 0) red[wv] = ss;
    __syncthreads();
    const float tot = red[0] + red[1] + red[2] + red[3];
    const float sc = rsqrtf(tot * (1.f / 1536.f) + 1e-6f);
    #pragma unroll
    for (int i = 0; i < 6; ++i) ip[i * 256 + t] = f2bf(v[i] * sc * w[i * 256 + t]);
}

// ---------------------------------------------------------------- q RoPE (table-driven)
__global__ __launch_bounds__(256) void qrope(
    const ushort* __restrict__ q, const float2* __restrict__ trig,
    ushort* __restrict__ qpe) {
    const int tok = blockIdx.x;
    const int s = tok & 2047;
    const int t = threadIdx.x;
    #pragma unroll
    for (int p = 0; p < 2; ++p) {
        const int idx = p * 256 + t;
        const int h = idx >> 5, i = idx & 31;
        const long base = (long)tok * 3072 + h * 192 + 128 + 2 * i;
        float x0 = bf2f(q[base]), x1 = bf2f(q[base + 1]);
        float2 cs = trig[s * 32 + i];
        const long ob = (long)tok * 1024 + h * 64 + 2 * i;
        qpe[ob]     = f2bf(x0 * cs.x - x1 * cs.y);
        qpe[ob + 1] = f2bf(x0 * cs.y + x1 * cs.x);
    }
}

// ---------------------------------------------------------------- kv prep: rmsnorm latent + k rope, from qk_comb cols [1536,2112)
__global__ __launch_bounds__(256) void kvprep(
    const ushort* __restrict__ qk, const float* __restrict__ w,
    const float2* __restrict__ trig, ushort* __restrict__ kvc,
    ushort* __restrict__ kpe) {
    const int tok = blockIdx.x;
    const int s = tok & 2047;
    const int t = threadIdx.x;
    const int lane = t & 63, wv = t >> 6;
    const ushort* in2 = qk + (long)tok * 2176 + 1536;
    const float v0 = bf2f(in2[t]);
    const float v1 = bf2f(in2[256 + t]);
    float ss = v0 * v0 + v1 * v1;
    #pragma unroll
    for (int off = 32; off > 0; off >>= 1) ss += __shfl_xor(ss, off);
    __shared__ float red[4];
    if (lane == 0) red[wv] = ss;
    __syncthreads();
    const float tot = red[0] + red[1] + red[2] + red[3];
    const float sc = rsqrtf(tot * (1.f / 512.f) + 1e-6f);
    kvc[(long)tok * 512 + t] = f2bf(v0 * sc * w[t]);
    kvc[(long)tok * 512 + 256 + t] = f2bf(v1 * sc * w[256 + t]);
    if (t < 32) {
        float x0 = bf2f(in2[512 + 2 * t]);
        float x1 = bf2f(in2[512 + 2 * t + 1]);
        float2 cs = trig[s * 32 + t];
        kpe[(long)tok * 64 + 2 * t]     = f2bf(x0 * cs.x - x1 * cs.y);
        kpe[(long)tok * 64 + 2 * t + 1] = f2bf(x0 * cs.y + x1 * cs.x);
    }
}

// ---------------------------------------------------------------- flash attention, non-absorbed (per-head MHA)
// Verified round-3 structure (110 us): padded Ks (200-stride, no swizzle), reg-staged
// K-tile (serial, NO cross-iter prefetch — T14 spilled at this VGPR budget, r7),
// diag-only causal mask, exp2-domain softmax, native cvt for P/epilogue stores.
// D_QK = 192 (128 nope + 64 rope in Ks), D_V = 128. Q-tile 64, KV-tile 128.
// Grid (16,16,2); block handles q-tiles {qx, 31-qx} -> 17 kv-iters (perfect balance).
// XCD remap keeps each (b,h) group on one XCD (kn+vT slice L2-resident).
__global__ __launch_bounds__(256, 2) void mha_attn(
    const ushort* __restrict__ q,      // (4096,3072): per-head 192, [0,128) nope
    const ushort* __restrict__ qpe,    // (4096,16,64) roped
    const ushort* __restrict__ kn,     // (2,2048,2048): k_nope, col h*128+d
    const ushort* __restrict__ kpe,    // (4096,64) roped, shared across heads
    const ushort* __restrict__ vT,     // (2,16,128,2048)
    ushort* __restrict__ o2) {         // (4096,2048): col h*128+d
    __shared__ __align__(16) ushort Ks[128][200];   // cols 0-127 nope, 128-191 rope
    __shared__ __align__(16) ushort P[64][136];     // cols 128-129 alpha(f32), 132-133 l(f32)
    // ---- XCD-aware bijective remap of (qx, h, b) ----
    const int fid = blockIdx.x + (blockIdx.y << 4) + (blockIdx.z << 8);  // 0..511
    const int xcd = fid & 7, j = fid >> 3;          // 64 blocks per XCD chunk
    const int g = xcd * 4 + (j >> 4);               // (b,h) group 0..31
    const int qx = j & 15, h = g & 15, b = g >> 4;
    const int tid = threadIdx.x, lane = tid & 63, w = tid >> 6;
    const int lrow = lane & 15, quad = lane >> 4;
    const long bb = (long)b * 2048;
    const float scale = 0.07216878364870323f * 1.4426950408889634f;  // 192^-0.5 * log2(e)
    const int rn = tid >> 4, cn = (tid & 15) * 8;   // nope staging: 16 lanes/row (256B rows)
    const int rr = tid >> 3, cr = (tid & 7) * 8;    // rope staging: 8 lanes/row (128B rows)

    for (int half = 0; half < 2; ++half) {
        const int qt = half ? (31 - qx) : qx;
        const int qrow = qt * 64;
        const long tokb = bb + qrow;

        bf16x8 qa[6];
        {
            const ushort* qp_ = q + (tokb + w * 16 + lrow) * 3072 + h * 192 + quad * 8;
            #pragma unroll
            for (int ks = 0; ks < 4; ++ks) qa[ks] = ldb8(qp_ + ks * 32);
            const ushort* qq = qpe + (tokb + w * 16 + lrow) * 1024 + h * 64 + quad * 8;
            qa[4] = ldb8(qq); qa[5] = ldb8(qq + 32);
        }

        floatx4 oacc[4][2] = {};     // [m-frag][v-frag]; wave owns v-dims [w*32, w*32+32)
        float m_i[4], l_i[4];
        #pragma unroll
        for (int r = 0; r < 4; ++r) { m_i[r] = -1e30f; l_i[r] = 0.f; }

        const int niter = qt / 2 + 1;
        for (int t = 0; t < niter; ++t) {
            const int kv0 = t * 128;
            // ---- stage K-tile (128 kv x (128 nope + 64 rope)) into LDS ----
            {
                const ushort* src = kn + (bb + kv0 + rn) * 2048 + h * 128 + cn;
                #pragma unroll
                for (int j2 = 0; j2 < 8; ++j2) {
                    uint4 v = *(const uint4*)(src + (long)j2 * 16 * 2048);
                    *(uint4*)&Ks[j2 * 16 + rn][cn] = v;
                }
                const ushort* srp = kpe + (bb + kv0 + rr) * 64 + cr;
                #pragma unroll
                for (int j2 = 0; j2 < 4; ++j2) {
                    uint4 v = *(const uint4*)(srp + (long)j2 * 32 * 64);
                    *(uint4*)&Ks[j2 * 32 + rr][128 + cr] = v;
                }
            }
            __syncthreads();  // A: stage visible; prev-iter P reads done

            // ---- QK^T: wave w owns q-rows [w*16, w*16+16), all 128 kv cols ----
            floatx4 sacc[8] = {};
            __builtin_amdgcn_s_setprio(1);
            #pragma unroll
            for (int f = 0; f < 8; ++f)
                #pragma unroll
                for (int ks = 0; ks < 6; ++ks)
                    sacc[f] = MFMA(qa[ks], ldb8(&Ks[f * 16 + lrow][ks * 32 + quad * 8]), sacc[f]);
            __builtin_amdgcn_s_setprio(0);

            // ---- prefetch V b-frags (L2-resident after remap) ----
            bf16x8 vf[2][4];
            {
                const ushort* vb = vT + ((long)(b * 16 + h)) * 262144 + (long)(w * 32 + lrow) * 2048 + kv0 + quad * 8;
                #pragma unroll
                for (int nf = 0; nf < 2; ++nf)
                    #pragma unroll
                    for (int kk = 0; kk < 4; ++kk)
                        vf[nf][kk] = ldb8(vb + (long)nf * 16 * 2048 + kk * 32);
            }

            // ---- online softmax (log2 domain) over 128 kv cols ----
            const bool diag = (t == niter - 1);
            #pragma unroll
            for (int r = 0; r < 4; ++r) {
                const int rloc = w * 16 + quad * 4 + r;
                const int row_s = qrow + rloc;
                float pv[8];
                float smax = -1e30f;
                #pragma unroll
                for (int f = 0; f < 8; ++f) {
                    pv[f] = sacc[f][r] * scale;
                    if (diag) { if (kv0 + f * 16 + lrow > row_s) pv[f] = -1e30f; }
                    smax = fmaxf(smax, pv[f]);
                }
                #pragma unroll
                for (int off = 1; off < 16; off <<= 1)
                    smax = fmaxf(smax, __shfl_xor(smax, off));
                const float mnew = fmaxf(m_i[r], smax);
                const float alpha = __builtin_amdgcn_exp2f(m_i[r] - mnew);
                float ps = 0.f;
                #pragma unroll
                for (int f = 0; f < 8; ++f) {
                    float p = __builtin_amdgcn_exp2f(pv[f] - mnew);
                    P[rloc][f * 16 + lrow] = f2bf_n(p);
                    ps += p;
                }
                #pragma unroll
                for (int off = 1; off < 16; off <<= 1)
                    ps += __shfl_xor(ps, off);
                l_i[r] = l_i[r] * alpha + ps;
                m_i[r] = mnew;
                if (lrow == 0) *(float*)&P[rloc][128] = alpha;
            }
            __syncthreads();  // B: P + alpha visible

            // ---- PV: wave w owns v-dims [w*32, +32), all 64 q-rows ----
            __builtin_amdgcn_s_setprio(1);
            #pragma unroll
            for (int mf = 0; mf < 4; ++mf) {
                float al[4];
                #pragma unroll
                for (int r = 0; r < 4; ++r) al[r] = *(const float*)&P[mf * 16 + quad * 4 + r][128];
                const int need = (al[0] != 1.f) | (al[1] != 1.f) | (al[2] != 1.f) | (al[3] != 1.f);
                if (__any(need)) {
                    #pragma unroll
                    for (int nf = 0; nf < 2; ++nf)
                        #pragma unroll
                        for (int r = 0; r < 4; ++r) oacc[mf][nf][r] *= al[r];
                }
                #pragma unroll
                for (int kk = 0; kk < 4; ++kk) {
                    bf16x8 pf = ldb8(&P[mf * 16 + lrow][kk * 32 + quad * 8]);
                    oacc[mf][0] = MFMA(pf, vf[0][kk], oacc[mf][0]);
                    oacc[mf][1] = MFMA(pf, vf[1][kk], oacc[mf][1]);
                }
            }
            __builtin_amdgcn_s_setprio(0);
        }

        // ---- epilogue ----
        #pragma unroll
        for (int r = 0; r < 4; ++r)
            if (lrow == 0) *(float*)&P[w * 16 + quad * 4 + r][132] = l_i[r];
        __syncthreads();
        #pragma unroll
        for (int mf = 0; mf < 4; ++mf) {
            float li[4];
            #pragma unroll
            for (int r = 0; r < 4; ++r) li[r] = *(const float*)&P[mf * 16 + quad * 4 + r][132];
            #pragma unroll
            for (int nf = 0; nf < 2; ++nf)
                #pragma unroll
                for (int r = 0; r < 4; ++r) {
                    long tok = tokb + mf * 16 + quad * 4 + r;
                    o2[tok * 2048 + h * 128 + w * 32 + nf * 16 + lrow] = f2bf_n(oacc[mf][nf][r] / li[r]);
                }
        }
        __syncthreads();  // protect P/Ks before next half
    }
}

// ---------------------------------------------------------------- launcher
extern "C" void kernel_launch(void* const* d_in, const int* in_sizes, int n_in,
                              void* d_out, int out_size, void* d_ws, size_t ws_size,
                              hipStream_t stream) {
    const float* x      = (const float*)d_in[0];
    const float* freqs  = (const float*)d_in[1];
    const float* wq_a   = (const float*)d_in[3];
    const float* qnw    = (const float*)d_in[4];
    const float* wq_b   = (const float*)d_in[5];
    const float* wkv_a  = (const float*)d_in[6];
    const float* kvnw   = (const float*)d_in[7];
    const float* wkv_b  = (const float*)d_in[8];
    const float* wo     = (const float*)d_in[9];
    float* out = (float*)d_out;
    (void)ws_size; (void)in_sizes; (void)n_in; (void)out_size;

    char* ws = (char*)d_ws;
    // lifetimes: qk_comb dies after kvprep -> o2 overlays it.
    //            xb dies after combined GEMM -> knope overlays it.
    ushort* qk_comb = (ushort*)(ws + 0);            // 4096x2176 bf16 = 17,825,792
    ushort* o2      = (ushort*)(ws + 0);            // 16,777,216 (after kvprep)
    ushort* xb      = (ushort*)(ws + 17825792);     // 16,777,216
    ushort* knope   = (ushort*)(ws + 17825792);     // 16,777,216 (after comb GEMM)
    ushort* q       = (ushort*)(ws + 34603008);     // 25,165,824
    ushort* qpe     = (ushort*)(ws + 59768832);     // 8,388,608
    ushort* kvc     = (ushort*)(ws + 68157440);     // 4,194,304
    ushort* kpe     = (ushort*)(ws + 72351744);     // 524,288
    ushort* vT      = (ushort*)(ws + 72876032);     // 16,777,216
    ushort* wcombT  = (ushort*)(ws + 89653248);     // 2176x2048 bf16 = 8,912,896
    ushort* wq_bT   = (ushort*)(ws + 98566144);     // 9,437,184
    ushort* wkv_bT  = (ushort*)(ws + 108003328);    // 4,194,304
    ushort* woT     = (ushort*)(ws + 112197632);    // 8,388,608
    float2* trig    = (float2*)(ws + 120586240);    // 524,288 -> ends 121,110,528

    dim3 tb(32, 8);
    trigtab<<<256, 256, 0, stream>>>(freqs, trig);
    // concat transposed weights: rows 0-1535 = wq_a^T, rows 1536-2111 = wkv_a^T, 2112-2175 pad
    transpose_f32_bf16<<<dim3(48, 64), tb, 0, stream>>>(wq_a, wcombT, 2048, 1536);
    transpose_f32_bf16<<<dim3(18, 64), tb, 0, stream>>>(wkv_a, wcombT + 1536L * 2048, 2048, 576);
    transpose_f32_bf16<<<dim3(96, 48), tb, 0, stream>>>(wq_b, wq_bT, 1536, 3072);
    transpose_f32_bf16<<<dim3(128, 16), tb, 0, stream>>>(wkv_b, wkv_bT, 512, 4096);
    transpose_f32_bf16<<<dim3(64, 64), tb, 0, stream>>>(wo, woT, 2048, 2048);
    cvt_f32_bf16<<<8192, 256, 0, stream>>>(x, xb, 8388608L);

    // qk_comb = x @ [wq_a | wkv_a]   (4096 x 2176, K=2048; cols 2112+ junk)
    gemm_bt128<<<dim3(17, 32, 1), 256, 0, stream>>>(xb, wcombT, qk_comb, 2048, 2048, 2048, 2176, 0, 0, 0, 0);
    // rmsnorm cols [0,1536) in place
    rms1536<<<4096, 256, 0, stream>>>(qk_comb, qnw);
    // q = qn @ wq_b               (4096 x 3072, K=1536; A stride 2176)
    gemm_bt128<<<dim3(24, 32, 1), 256, 0, stream>>>(qk_comb, wq_bT, q, 1536, 2176, 1536, 3072, 0, 0, 0, 0);
    // q_pe = rope(q[..., 128:192])
    qrope<<<4096, 256, 0, stream>>>(q, trig, qpe);
    // kvc (rmsnormed latent) / kpe  from qk_comb cols [1536,2112)
    kvprep<<<4096, 256, 0, stream>>>(qk_comb, kvnw, trig, kvc, kpe);

    // k_nope[b,s,h*128+d] = sum_c kvc[b,s,c] * wkv_b[c, h*256+d]   (z = head, both batches)
    gemm_bt128<<<dim3(1, 32, 16), 256, 0, stream>>>(kvc, wkv_bT, knope,
        512, 512, 512, 2048, 0, 131072, 128, 0);
    // vT[b,h,d,s] = sum_c wkv_b[c, h*256+128+d] * kvc[b,s,c]       (z = head)
    gemm_bt128<<<dim3(16, 1, 16), 256, 0, stream>>>(wkv_bT + 65536, kvc, vT,
        512, 512, 512, 2048, 131072, 0, 262144, 0);
    gemm_bt128<<<dim3(16, 1, 16), 256, 0, stream>>>(wkv_bT + 65536, kvc + 1048576, vT + 4194304,
        512, 512, 512, 2048, 131072, 0, 262144, 0);

    // flash attention (non-absorbed), writes per-head O directly
    mha_attn<<<dim3(16, 16, 2), 256, 0, stream>>>(q, qpe, knope, kpe, vT, o2);

    // out = o2 @ wo (fp32 output)
    gemm_bt128<<<dim3(16, 32, 1), 256, 0, stream>>>(o2, woT, out, 2048, 2048, 2048, 2048, 0, 0, 0, 1);
}

// Round 9
// 477.974 us; speedup vs baseline: 1.1614x; 1.0028x over previous
//
#include <hip/hip_runtime.h>

typedef __bf16 bf16x8 __attribute__((ext_vector_type(8)));
typedef float floatx4 __attribute__((ext_vector_type(4)));

#define MFMA(a, b, c) __builtin_amdgcn_mfma_f32_16x16x32_bf16((a), (b), (c), 0, 0, 0)

__device__ __forceinline__ float bf2f(ushort u) {
    union { unsigned int i; float f; } v; v.i = ((unsigned int)u) << 16; return v.f;
}
__device__ __forceinline__ ushort f2bf(float f) {
    union { float f; unsigned int i; } v; v.f = f;
    unsigned int r = v.i + 0x7fffu + ((v.i >> 16) & 1u);
    return (ushort)(r >> 16);
}
// native RTNE convert — attention hot path
__device__ __forceinline__ ushort f2bf_n(float f) {
    union { __bf16 b; ushort u; } v; v.b = (__bf16)f; return v.u;
}
__device__ __forceinline__ bf16x8 ldb8(const ushort* p) { return *(const bf16x8*)p; }

// ---------------------------------------------------------------- fp32 -> bf16 transpose
__global__ __launch_bounds__(256) void transpose_f32_bf16(
    const float* __restrict__ in, ushort* __restrict__ out, int R, int C) {
    __shared__ ushort tile[32][33];
    const int c0 = blockIdx.x * 32, r0 = blockIdx.y * 32;
    const int tx = threadIdx.x, ty = threadIdx.y;
    #pragma unroll
    for (int i = 0; i < 32; i += 8) {
        int r = r0 + ty + i, c = c0 + tx;
        if (r < R && c < C) tile[ty + i][tx] = f2bf(in[(long)r * C + c]);
    }
    __syncthreads();
    #pragma unroll
    for (int i = 0; i < 32; i += 8) {
        int r = c0 + ty + i, c = r0 + tx;   // out is C x R
        if (r < C && c < R) out[(long)r * R + c] = tile[tx][ty + i];
    }
}

// ---------------------------------------------------------------- fp32 -> bf16 elementwise (n % 4 == 0)
__global__ __launch_bounds__(256) void cvt_f32_bf16(
    const float* __restrict__ in, ushort* __restrict__ out, long n) {
    const long i = ((long)blockIdx.x * 256 + threadIdx.x) * 4;
    if (i >= n) return;
    float4 v = *(const float4*)(in + i);
    ushort4 o;
    o.x = f2bf(v.x); o.y = f2bf(v.y); o.z = f2bf(v.z); o.w = f2bf(v.w);
    *(ushort4*)(out + i) = o;
}

// ---------------------------------------------------------------- trig table: freqs -> (cos, sin)
__global__ __launch_bounds__(256) void trigtab(
    const float* __restrict__ freqs, float2* __restrict__ trig) {
    const int idx = blockIdx.x * 256 + threadIdx.x;   // 2048*32 = 65536
    float th = freqs[idx];
    trig[idx] = make_float2(cosf(th), sinf(th));
}

// ---------------------------------------------------------------- GEMM 128-tile, global_load_lds (m97-class)
__global__ __launch_bounds__(256, 3) void gemm_bt128(
    const ushort* __restrict__ A, const ushort* __restrict__ Bt,
    void* __restrict__ C, int K, int lda, int ldb, int ldc,
    long aZ, long bZ, long cZ, int c_f32) {
    __shared__ __align__(16) ushort As[128 * 64];
    __shared__ __align__(16) ushort Bs[128 * 64];
    const int z = blockIdx.z;
    const ushort* Ab = A + (long)z * aZ;
    const ushort* Bb = Bt + (long)z * bZ;
    const long m0 = (long)blockIdx.y * 128;
    const long n0 = (long)blockIdx.x * 128;
    const int tid = threadIdx.x;
    const int lane = tid & 63, w = tid >> 6;
    const int wm = (w >> 1) * 64, wn = (w & 1) * 64;
    const int lrow = lane & 15, quad = lane >> 4;

    floatx4 acc[4][4] = {};

    for (int k0 = 0; k0 < K; k0 += 64) {
        __syncthreads();
        #pragma unroll
        for (int t = 0; t < 4; ++t) {
            const int c = t * 256 + tid;
            const int r = c >> 3, kc = (c & 7) * 8;
            __builtin_amdgcn_global_load_lds(
                (const __attribute__((address_space(1))) unsigned int*)(Ab + (m0 + r) * lda + k0 + kc),
                (__attribute__((address_space(3))) unsigned int*)(As + (long)c * 8), 16, 0, 0);
            __builtin_amdgcn_global_load_lds(
                (const __attribute__((address_space(1))) unsigned int*)(Bb + (n0 + r) * ldb + k0 + kc),
                (__attribute__((address_space(3))) unsigned int*)(Bs + (long)c * 8), 16, 0, 0);
        }
        __syncthreads();
        #pragma unroll
        for (int kk = 0; kk < 64; kk += 32) {
            bf16x8 af[4], bv[4];
            #pragma unroll
            for (int i = 0; i < 4; ++i) {
                af[i] = ldb8(&As[(wm + i * 16 + lrow) * 64 + kk + quad * 8]);
                bv[i] = ldb8(&Bs[(wn + i * 16 + lrow) * 64 + kk + quad * 8]);
            }
            #pragma unroll
            for (int i = 0; i < 4; ++i)
                #pragma unroll
                for (int j = 0; j < 4; ++j)
                    acc[i][j] = MFMA(af[i], bv[j], acc[i][j]);
        }
    }
    if (c_f32) {
        float* Cb = (float*)C + (long)z * cZ;
        #pragma unroll
        for (int mt = 0; mt < 4; ++mt)
            #pragma unroll
            for (int nt = 0; nt < 4; ++nt)
                #pragma unroll
                for (int r = 0; r < 4; ++r)
                    Cb[(m0 + wm + mt * 16 + quad * 4 + r) * ldc + n0 + wn + nt * 16 + lrow] = acc[mt][nt][r];
    } else {
        ushort* Cb = (ushort*)C + (long)z * cZ;
        #pragma unroll
        for (int mt = 0; mt < 4; ++mt)
            #pragma unroll
            for (int nt = 0; nt < 4; ++nt)
                #pragma unroll
                for (int r = 0; r < 4; ++r)
                    Cb[(m0 + wm + mt * 16 + quad * 4 + r) * ldc + n0 + wn + nt * 16 + lrow] = f2bf(acc[mt][nt][r]);
    }
}

// ---------------------------------------------------------------- RMSNorm over cols [0,1536) of 2176-stride rows (in-place)
__global__ __launch_bounds__(256) void rms1536(
    ushort* qk, const float* __restrict__ w) {
    const int row = blockIdx.x, t = threadIdx.x;
    const int lane = t & 63, wv = t >> 6;
    ushort* ip = qk + (long)row * 2176;
    float v[6]; float ss = 0.f;
    #pragma unroll
    for (int i = 0; i < 6; ++i) { v[i] = bf2f(ip[i * 256 + t]); ss += v[i] * v[i]; }
    #pragma unroll
    for (int off = 32; off > 0; off >>= 1) ss += __shfl_xor(ss, off);
    __shared__ float red[4];
    if (lane == 0) red[wv] = ss;
    __syncthreads();
    const float tot = red[0] + red[1] + red[2] + red[3];
    const float sc = rsqrtf(tot * (1.f / 1536.f) + 1e-6f);
    #pragma unroll
    for (int i = 0; i < 6; ++i) ip[i * 256 + t] = f2bf(v[i] * sc * w[i * 256 + t]);
}

// ---------------------------------------------------------------- q RoPE (table-driven)
__global__ __launch_bounds__(256) void qrope(
    const ushort* __restrict__ q, const float2* __restrict__ trig,
    ushort* __restrict__ qpe) {
    const int tok = blockIdx.x;
    const int s = tok & 2047;
    const int t = threadIdx.x;
    #pragma unroll
    for (int p = 0; p < 2; ++p) {
        const int idx = p * 256 + t;
        const int h = idx >> 5, i = idx & 31;
        const long base = (long)tok * 3072 + h * 192 + 128 + 2 * i;
        float x0 = bf2f(q[base]), x1 = bf2f(q[base + 1]);
        float2 cs = trig[s * 32 + i];
        const long ob = (long)tok * 1024 + h * 64 + 2 * i;
        qpe[ob]     = f2bf(x0 * cs.x - x1 * cs.y);
        qpe[ob + 1] = f2bf(x0 * cs.y + x1 * cs.x);
    }
}

// ---------------------------------------------------------------- kv prep: rmsnorm latent + k rope, from qk_comb cols [1536,2112)
__global__ __launch_bounds__(256) void kvprep(
    const ushort* __restrict__ qk, const float* __restrict__ w,
    const float2* __restrict__ trig, ushort* __restrict__ kvc,
    ushort* __restrict__ kpe) {
    const int tok = blockIdx.x;
    const int s = tok & 2047;
    const int t = threadIdx.x;
    const int lane = t & 63, wv = t >> 6;
    const ushort* in2 = qk + (long)tok * 2176 + 1536;
    const float v0 = bf2f(in2[t]);
    const float v1 = bf2f(in2[256 + t]);
    float ss = v0 * v0 + v1 * v1;
    #pragma unroll
    for (int off = 32; off > 0; off >>= 1) ss += __shfl_xor(ss, off);
    __shared__ float red[4];
    if (lane == 0) red[wv] = ss;
    __syncthreads();
    const float tot = red[0] + red[1] + red[2] + red[3];
    const float sc = rsqrtf(tot * (1.f / 512.f) + 1e-6f);
    kvc[(long)tok * 512 + t] = f2bf(v0 * sc * w[t]);
    kvc[(long)tok * 512 + 256 + t] = f2bf(v1 * sc * w[256 + t]);
    if (t < 32) {
        float x0 = bf2f(in2[512 + 2 * t]);
        float x1 = bf2f(in2[512 + 2 * t + 1]);
        float2 cs = trig[s * 32 + t];
        kpe[(long)tok * 64 + 2 * t]     = f2bf(x0 * cs.x - x1 * cs.y);
        kpe[(long)tok * 64 + 2 * t + 1] = f2bf(x0 * cs.y + x1 * cs.x);
    }
}

// ---------------------------------------------------------------- flash attention, non-absorbed (per-head MHA)
// r8 banked structure (110 us) + T14 async-STAGE with NAMED scalar registers
// (r7's uint4 arrays went to scratch -> 375 MB writes; named vars force VGPRs).
// Issue next K-tile loads after barrier A (hidden under QK+softmax); LDS write
// after barrier B (all Ks(t) reads done; visible via next barrier A).
// D_QK = 192 (128 nope + 64 rope in Ks), D_V = 128. Q-tile 64, KV-tile 128.
// Grid (16,16,2); block handles q-tiles {qx, 31-qx} -> 17 kv-iters (perfect balance).
__global__ __launch_bounds__(256, 2) void mha_attn(
    const ushort* __restrict__ q,      // (4096,3072): per-head 192, [0,128) nope
    const ushort* __restrict__ qpe,    // (4096,16,64) roped
    const ushort* __restrict__ kn,     // (2,2048,2048): k_nope, col h*128+d
    const ushort* __restrict__ kpe,    // (4096,64) roped, shared across heads
    const ushort* __restrict__ vT,     // (2,16,128,2048)
    ushort* __restrict__ o2) {         // (4096,2048): col h*128+d
    __shared__ __align__(16) ushort Ks[128][200];   // cols 0-127 nope, 128-191 rope
    __shared__ __align__(16) ushort P[64][136];     // cols 128-129 alpha(f32), 132-133 l(f32)
    // ---- XCD-aware bijective remap of (qx, h, b) ----
    const int fid = blockIdx.x + (blockIdx.y << 4) + (blockIdx.z << 8);  // 0..511
    const int xcd = fid & 7, j = fid >> 3;          // 64 blocks per XCD chunk
    const int g = xcd * 4 + (j >> 4);               // (b,h) group 0..31
    const int qx = j & 15, h = g & 15, b = g >> 4;
    const int tid = threadIdx.x, lane = tid & 63, w = tid >> 6;
    const int lrow = lane & 15, quad = lane >> 4;
    const long bb = (long)b * 2048;
    const float scale = 0.07216878364870323f * 1.4426950408889634f;  // 192^-0.5 * log2(e)
    const int rn = tid >> 4, cn = (tid & 15) * 8;   // nope staging: 16 lanes/row (256B rows)
    const int rr = tid >> 3, cr = (tid & 7) * 8;    // rope staging: 8 lanes/row (128B rows)

    for (int half = 0; half < 2; ++half) {
        const int qt = half ? (31 - qx) : qx;
        const int qrow = qt * 64;
        const long tokb = bb + qrow;

        bf16x8 qa[6];
        {
            const ushort* qp_ = q + (tokb + w * 16 + lrow) * 3072 + h * 192 + quad * 8;
            #pragma unroll
            for (int ks = 0; ks < 4; ++ks) qa[ks] = ldb8(qp_ + ks * 32);
            const ushort* qq = qpe + (tokb + w * 16 + lrow) * 1024 + h * 64 + quad * 8;
            qa[4] = ldb8(qq); qa[5] = ldb8(qq + 32);
        }

        floatx4 oacc[4][2] = {};     // [m-frag][v-frag]; wave owns v-dims [w*32, w*32+32)
        float m_i[4], l_i[4];
        #pragma unroll
        for (int r = 0; r < 4; ++r) { m_i[r] = -1e30f; l_i[r] = 0.f; }

        const int niter = qt / 2 + 1;

        // ---- synchronous stage of K-tile 0 ----
        {
            const ushort* src = kn + (bb + rn) * 2048 + h * 128 + cn;
            #pragma unroll
            for (int j2 = 0; j2 < 8; ++j2)
                *(uint4*)&Ks[j2 * 16 + rn][cn] = *(const uint4*)(src + (long)j2 * 16 * 2048);
            const ushort* srp = kpe + (bb + rr) * 64 + cr;
            #pragma unroll
            for (int j2 = 0; j2 < 4; ++j2)
                *(uint4*)&Ks[j2 * 32 + rr][128 + cr] = *(const uint4*)(srp + (long)j2 * 32 * 64);
        }

        for (int t = 0; t < niter; ++t) {
            const int kv0 = t * 128;
            __syncthreads();  // A: Ks(t) visible; prev-iter P reads done

            // ---- T14 issue-early: next K-tile -> NAMED regs (hidden under QK+softmax) ----
            uint4 n0, n1, n2, n3, n4, n5, n6, n7, p0, p1, p2, p3;
            const bool pfv = (t + 1 < niter);
            if (pfv) {
                const ushort* src = kn + (bb + kv0 + 128 + rn) * 2048 + h * 128 + cn;
                n0 = *(const uint4*)(src);
                n1 = *(const uint4*)(src + 16L * 2048);
                n2 = *(const uint4*)(src + 32L * 2048);
                n3 = *(const uint4*)(src + 48L * 2048);
                n4 = *(const uint4*)(src + 64L * 2048);
                n5 = *(const uint4*)(src + 80L * 2048);
                n6 = *(const uint4*)(src + 96L * 2048);
                n7 = *(const uint4*)(src + 112L * 2048);
                const ushort* srp = kpe + (bb + kv0 + 128 + rr) * 64 + cr;
                p0 = *(const uint4*)(srp);
                p1 = *(const uint4*)(srp + 32L * 64);
                p2 = *(const uint4*)(srp + 64L * 64);
                p3 = *(const uint4*)(srp + 96L * 64);
            }

            // ---- QK^T: wave w owns q-rows [w*16, w*16+16), all 128 kv cols ----
            floatx4 sacc[8] = {};
            __builtin_amdgcn_s_setprio(1);
            #pragma unroll
            for (int f = 0; f < 8; ++f)
                #pragma unroll
                for (int ks = 0; ks < 6; ++ks)
                    sacc[f] = MFMA(qa[ks], ldb8(&Ks[f * 16 + lrow][ks * 32 + quad * 8]), sacc[f]);
            __builtin_amdgcn_s_setprio(0);

            // ---- prefetch V b-frags (L2/L3-resident) ----
            bf16x8 vf[2][4];
            {
                const ushort* vb = vT + ((long)(b * 16 + h)) * 262144 + (long)(w * 32 + lrow) * 2048 + kv0 + quad * 8;
                #pragma unroll
                for (int nf = 0; nf < 2; ++nf)
                    #pragma unroll
                    for (int kk = 0; kk < 4; ++kk)
                        vf[nf][kk] = ldb8(vb + (long)nf * 16 * 2048 + kk * 32);
            }

            // ---- online softmax (log2 domain) over 128 kv cols ----
            const bool diag = (t == niter - 1);
            #pragma unroll
            for (int r = 0; r < 4; ++r) {
                const int rloc = w * 16 + quad * 4 + r;
                const int row_s = qrow + rloc;
                float pv[8];
                float smax = -1e30f;
                #pragma unroll
                for (int f = 0; f < 8; ++f) {
                    pv[f] = sacc[f][r] * scale;
                    if (diag) { if (kv0 + f * 16 + lrow > row_s) pv[f] = -1e30f; }
                    smax = fmaxf(smax, pv[f]);
                }
                #pragma unroll
                for (int off = 1; off < 16; off <<= 1)
                    smax = fmaxf(smax, __shfl_xor(smax, off));
                const float mnew = fmaxf(m_i[r], smax);
                const float alpha = __builtin_amdgcn_exp2f(m_i[r] - mnew);
                float ps = 0.f;
                #pragma unroll
                for (int f = 0; f < 8; ++f) {
                    float p = __builtin_amdgcn_exp2f(pv[f] - mnew);
                    P[rloc][f * 16 + lrow] = f2bf_n(p);
                    ps += p;
                }
                #pragma unroll
                for (int off = 1; off < 16; off <<= 1)
                    ps += __shfl_xor(ps, off);
                l_i[r] = l_i[r] * alpha + ps;
                m_i[r] = mnew;
                if (lrow == 0) *(float*)&P[rloc][128] = alpha;
            }
            __syncthreads();  // B: P + alpha visible; all Ks(t) reads done

            // ---- T14 write-late: named regs -> LDS (overlaps PV; visible at next A) ----
            if (pfv) {
                *(uint4*)&Ks[rn][cn]        = n0;
                *(uint4*)&Ks[16 + rn][cn]   = n1;
                *(uint4*)&Ks[32 + rn][cn]   = n2;
                *(uint4*)&Ks[48 + rn][cn]   = n3;
                *(uint4*)&Ks[64 + rn][cn]   = n4;
                *(uint4*)&Ks[80 + rn][cn]   = n5;
                *(uint4*)&Ks[96 + rn][cn]   = n6;
                *(uint4*)&Ks[112 + rn][cn]  = n7;
                *(uint4*)&Ks[rr][128 + cr]       = p0;
                *(uint4*)&Ks[32 + rr][128 + cr]  = p1;
                *(uint4*)&Ks[64 + rr][128 + cr]  = p2;
                *(uint4*)&Ks[96 + rr][128 + cr]  = p3;
            }

            // ---- PV: wave w owns v-dims [w*32, +32), all 64 q-rows ----
            __builtin_amdgcn_s_setprio(1);
            #pragma unroll
            for (int mf = 0; mf < 4; ++mf) {
                float al[4];
                #pragma unroll
                for (int r = 0; r < 4; ++r) al[r] = *(const float*)&P[mf * 16 + quad * 4 + r][128];
                const int need = (al[0] != 1.f) | (al[1] != 1.f) | (al[2] != 1.f) | (al[3] != 1.f);
                if (__any(need)) {
                    #pragma unroll
                    for (int nf = 0; nf < 2; ++nf)
                        #pragma unroll
                        for (int r = 0; r < 4; ++r) oacc[mf][nf][r] *= al[r];
                }
                #pragma unroll
                for (int kk = 0; kk < 4; ++kk) {
                    bf16x8 pfr = ldb8(&P[mf * 16 + lrow][kk * 32 + quad * 8]);
                    oacc[mf][0] = MFMA(pfr, vf[0][kk], oacc[mf][0]);
                    oacc[mf][1] = MFMA(pfr, vf[1][kk], oacc[mf][1]);
                }
            }
            __builtin_amdgcn_s_setprio(0);
        }

        // ---- epilogue ----
        #pragma unroll
        for (int r = 0; r < 4; ++r)
            if (lrow == 0) *(float*)&P[w * 16 + quad * 4 + r][132] = l_i[r];
        __syncthreads();
        #pragma unroll
        for (int mf = 0; mf < 4; ++mf) {
            float li[4];
            #pragma unroll
            for (int r = 0; r < 4; ++r) li[r] = *(const float*)&P[mf * 16 + quad * 4 + r][132];
            #pragma unroll
            for (int nf = 0; nf < 2; ++nf)
                #pragma unroll
                for (int r = 0; r < 4; ++r) {
                    long tok = tokb + mf * 16 + quad * 4 + r;
                    o2[tok * 2048 + h * 128 + w * 32 + nf * 16 + lrow] = f2bf_n(oacc[mf][nf][r] / li[r]);
                }
        }
        __syncthreads();  // protect P/Ks before next half
    }
}

// ---------------------------------------------------------------- launcher
extern "C" void kernel_launch(void* const* d_in, const int* in_sizes, int n_in,
                              void* d_out, int out_size, void* d_ws, size_t ws_size,
                              hipStream_t stream) {
    const float* x      = (const float*)d_in[0];
    const float* freqs  = (const float*)d_in[1];
    const float* wq_a   = (const float*)d_in[3];
    const float* qnw    = (const float*)d_in[4];
    const float* wq_b   = (const float*)d_in[5];
    const float* wkv_a  = (const float*)d_in[6];
    const float* kvnw   = (const float*)d_in[7];
    const float* wkv_b  = (const float*)d_in[8];
    const float* wo     = (const float*)d_in[9];
    float* out = (float*)d_out;
    (void)ws_size; (void)in_sizes; (void)n_in; (void)out_size;

    char* ws = (char*)d_ws;
    // lifetimes: qk_comb dies after kvprep -> o2 overlays it.
    //            xb dies after combined GEMM -> knope overlays it.
    ushort* qk_comb = (ushort*)(ws + 0);            // 4096x2176 bf16 = 17,825,792
    ushort* o2      = (ushort*)(ws + 0);            // 16,777,216 (after kvprep)
    ushort* xb      = (ushort*)(ws + 17825792);     // 16,777,216
    ushort* knope   = (ushort*)(ws + 17825792);     // 16,777,216 (after comb GEMM)
    ushort* q       = (ushort*)(ws + 34603008);     // 25,165,824
    ushort* qpe     = (ushort*)(ws + 59768832);     // 8,388,608
    ushort* kvc     = (ushort*)(ws + 68157440);     // 4,194,304
    ushort* kpe     = (ushort*)(ws + 72351744);     // 524,288
    ushort* vT      = (ushort*)(ws + 72876032);     // 16,777,216
    ushort* wcombT  = (ushort*)(ws + 89653248);     // 2176x2048 bf16 = 8,912,896
    ushort* wq_bT   = (ushort*)(ws + 98566144);     // 9,437,184
    ushort* wkv_bT  = (ushort*)(ws + 108003328);    // 4,194,304
    ushort* woT     = (ushort*)(ws + 112197632);    // 8,388,608
    float2* trig    = (float2*)(ws + 120586240);    // 524,288 -> ends 121,110,528

    dim3 tb(32, 8);
    trigtab<<<256, 256, 0, stream>>>(freqs, trig);
    // concat transposed weights: rows 0-1535 = wq_a^T, rows 1536-2111 = wkv_a^T, 2112-2175 pad
    transpose_f32_bf16<<<dim3(48, 64), tb, 0, stream>>>(wq_a, wcombT, 2048, 1536);
    transpose_f32_bf16<<<dim3(18, 64), tb, 0, stream>>>(wkv_a, wcombT + 1536L * 2048, 2048, 576);
    transpose_f32_bf16<<<dim3(96, 48), tb, 0, stream>>>(wq_b, wq_bT, 1536, 3072);
    transpose_f32_bf16<<<dim3(128, 16), tb, 0, stream>>>(wkv_b, wkv_bT, 512, 4096);
    transpose_f32_bf16<<<dim3(64, 64), tb, 0, stream>>>(wo, woT, 2048, 2048);
    cvt_f32_bf16<<<8192, 256, 0, stream>>>(x, xb, 8388608L);

    // qk_comb = x @ [wq_a | wkv_a]   (4096 x 2176, K=2048; cols 2112+ junk)
    gemm_bt128<<<dim3(17, 32, 1), 256, 0, stream>>>(xb, wcombT, qk_comb, 2048, 2048, 2048, 2176, 0, 0, 0, 0);
    // rmsnorm cols [0,1536) in place
    rms1536<<<4096, 256, 0, stream>>>(qk_comb, qnw);
    // q = qn @ wq_b               (4096 x 3072, K=1536; A stride 2176)
    gemm_bt128<<<dim3(24, 32, 1), 256, 0, stream>>>(qk_comb, wq_bT, q, 1536, 2176, 1536, 3072, 0, 0, 0, 0);
    // q_pe = rope(q[..., 128:192])
    qrope<<<4096, 256, 0, stream>>>(q, trig, qpe);
    // kvc (rmsnormed latent) / kpe  from qk_comb cols [1536,2112)
    kvprep<<<4096, 256, 0, stream>>>(qk_comb, kvnw, trig, kvc, kpe);

    // k_nope[b,s,h*128+d] = sum_c kvc[b,s,c] * wkv_b[c, h*256+d]   (z = head, both batches)
    gemm_bt128<<<dim3(1, 32, 16), 256, 0, stream>>>(kvc, wkv_bT, knope,
        512, 512, 512, 2048, 0, 131072, 128, 0);
    // vT[b,h,d,s] = sum_c wkv_b[c, h*256+128+d] * kvc[b,s,c]       (z = head)
    gemm_bt128<<<dim3(16, 1, 16), 256, 0, stream>>>(wkv_bT + 65536, kvc, vT,
        512, 512, 512, 2048, 131072, 0, 262144, 0);
    gemm_bt128<<<dim3(16, 1, 16), 256, 0, stream>>>(wkv_bT + 65536, kvc + 1048576, vT + 4194304,
        512, 512, 512, 2048, 131072, 0, 262144, 0);

    // flash attention (non-absorbed), writes per-head O directly
    mha_attn<<<dim3(16, 16, 2), 256, 0, stream>>>(q, qpe, knope, kpe, vT, o2);

    // out = o2 @ wo (fp32 output)
    gemm_bt128<<<dim3(16, 32, 1), 256, 0, stream>>>(o2, woT, out, 2048, 2048, 2048, 2048, 0, 0, 0, 1);
}

// Round 10
// 471.610 us; speedup vs baseline: 1.1771x; 1.0135x over previous
//
#include <hip/hip_runtime.h>

typedef __bf16 bf16x8 __attribute__((ext_vector_type(8)));
typedef float floatx4 __attribute__((ext_vector_type(4)));

#define MFMA(a, b, c) __builtin_amdgcn_mfma_f32_16x16x32_bf16((a), (b), (c), 0, 0, 0)

__device__ __forceinline__ float bf2f(ushort u) {
    union { unsigned int i; float f; } v; v.i = ((unsigned int)u) << 16; return v.f;
}
__device__ __forceinline__ ushort f2bf(float f) {
    union { float f; unsigned int i; } v; v.f = f;
    unsigned int r = v.i + 0x7fffu + ((v.i >> 16) & 1u);
    return (ushort)(r >> 16);
}
// native RTNE convert — attention hot path
__device__ __forceinline__ ushort f2bf_n(float f) {
    union { __bf16 b; ushort u; } v; v.b = (__bf16)f; return v.u;
}
__device__ __forceinline__ bf16x8 ldb8(const ushort* p) { return *(const bf16x8*)p; }

// ---------------------------------------------------------------- fp32 -> bf16 transpose
__global__ __launch_bounds__(256) void transpose_f32_bf16(
    const float* __restrict__ in, ushort* __restrict__ out, int R, int C) {
    __shared__ ushort tile[32][33];
    const int c0 = blockIdx.x * 32, r0 = blockIdx.y * 32;
    const int tx = threadIdx.x, ty = threadIdx.y;
    #pragma unroll
    for (int i = 0; i < 32; i += 8) {
        int r = r0 + ty + i, c = c0 + tx;
        if (r < R && c < C) tile[ty + i][tx] = f2bf(in[(long)r * C + c]);
    }
    __syncthreads();
    #pragma unroll
    for (int i = 0; i < 32; i += 8) {
        int r = c0 + ty + i, c = r0 + tx;   // out is C x R
        if (r < C && c < R) out[(long)r * R + c] = tile[tx][ty + i];
    }
}

// ---------------------------------------------------------------- fp32 -> bf16 elementwise (n % 4 == 0)
__global__ __launch_bounds__(256) void cvt_f32_bf16(
    const float* __restrict__ in, ushort* __restrict__ out, long n) {
    const long i = ((long)blockIdx.x * 256 + threadIdx.x) * 4;
    if (i >= n) return;
    float4 v = *(const float4*)(in + i);
    ushort4 o;
    o.x = f2bf(v.x); o.y = f2bf(v.y); o.z = f2bf(v.z); o.w = f2bf(v.w);
    *(ushort4*)(out + i) = o;
}

// ---------------------------------------------------------------- trig table: freqs -> (cos, sin)
__global__ __launch_bounds__(256) void trigtab(
    const float* __restrict__ freqs, float2* __restrict__ trig) {
    const int idx = blockIdx.x * 256 + threadIdx.x;   // 2048*32 = 65536
    float th = freqs[idx];
    trig[idx] = make_float2(cosf(th), sinf(th));
}

// ---------------------------------------------------------------- GEMM 128-tile, global_load_lds (m97-class)
__global__ __launch_bounds__(256, 3) void gemm_bt128(
    const ushort* __restrict__ A, const ushort* __restrict__ Bt,
    void* __restrict__ C, int K, int lda, int ldb, int ldc,
    long aZ, long bZ, long cZ, int c_f32) {
    __shared__ __align__(16) ushort As[128 * 64];
    __shared__ __align__(16) ushort Bs[128 * 64];
    const int z = blockIdx.z;
    const ushort* Ab = A + (long)z * aZ;
    const ushort* Bb = Bt + (long)z * bZ;
    const long m0 = (long)blockIdx.y * 128;
    const long n0 = (long)blockIdx.x * 128;
    const int tid = threadIdx.x;
    const int lane = tid & 63, w = tid >> 6;
    const int wm = (w >> 1) * 64, wn = (w & 1) * 64;
    const int lrow = lane & 15, quad = lane >> 4;

    floatx4 acc[4][4] = {};

    for (int k0 = 0; k0 < K; k0 += 64) {
        __syncthreads();
        #pragma unroll
        for (int t = 0; t < 4; ++t) {
            const int c = t * 256 + tid;
            const int r = c >> 3, kc = (c & 7) * 8;
            __builtin_amdgcn_global_load_lds(
                (const __attribute__((address_space(1))) unsigned int*)(Ab + (m0 + r) * lda + k0 + kc),
                (__attribute__((address_space(3))) unsigned int*)(As + (long)c * 8), 16, 0, 0);
            __builtin_amdgcn_global_load_lds(
                (const __attribute__((address_space(1))) unsigned int*)(Bb + (n0 + r) * ldb + k0 + kc),
                (__attribute__((address_space(3))) unsigned int*)(Bs + (long)c * 8), 16, 0, 0);
        }
        __syncthreads();
        #pragma unroll
        for (int kk = 0; kk < 64; kk += 32) {
            bf16x8 af[4], bv[4];
            #pragma unroll
            for (int i = 0; i < 4; ++i) {
                af[i] = ldb8(&As[(wm + i * 16 + lrow) * 64 + kk + quad * 8]);
                bv[i] = ldb8(&Bs[(wn + i * 16 + lrow) * 64 + kk + quad * 8]);
            }
            #pragma unroll
            for (int i = 0; i < 4; ++i)
                #pragma unroll
                for (int j = 0; j < 4; ++j)
                    acc[i][j] = MFMA(af[i], bv[j], acc[i][j]);
        }
    }
    if (c_f32) {
        float* Cb = (float*)C + (long)z * cZ;
        #pragma unroll
        for (int mt = 0; mt < 4; ++mt)
            #pragma unroll
            for (int nt = 0; nt < 4; ++nt)
                #pragma unroll
                for (int r = 0; r < 4; ++r)
                    Cb[(m0 + wm + mt * 16 + quad * 4 + r) * ldc + n0 + wn + nt * 16 + lrow] = acc[mt][nt][r];
    } else {
        ushort* Cb = (ushort*)C + (long)z * cZ;
        #pragma unroll
        for (int mt = 0; mt < 4; ++mt)
            #pragma unroll
            for (int nt = 0; nt < 4; ++nt)
                #pragma unroll
                for (int r = 0; r < 4; ++r)
                    Cb[(m0 + wm + mt * 16 + quad * 4 + r) * ldc + n0 + wn + nt * 16 + lrow] = f2bf(acc[mt][nt][r]);
    }
}

// ---------------------------------------------------------------- vT GEMM, both batches in one launch
// z = b*16+h. vT[b,h,d,s] = sum_c wkv_b[c, h*256+128+d] * kvc[b,s,c].
// A = Wb + h*131072 (M=128 rows, lda=512); B = kvc + b*1048576 (ldb=512);
// C = vT + b*4194304 + h*262144 (ldc=2048, N=2048 via blockIdx.x).
__global__ __launch_bounds__(256, 3) void gemm_vt(
    const ushort* __restrict__ Wb, const ushort* __restrict__ kvc,
    ushort* __restrict__ vT) {
    __shared__ __align__(16) ushort As[128 * 64];
    __shared__ __align__(16) ushort Bs[128 * 64];
    const int z = blockIdx.z, b = z >> 4, h = z & 15;
    const ushort* Ab = Wb + (long)h * 131072;
    const ushort* Bb = kvc + (long)b * 1048576;
    ushort* Cb = vT + (long)b * 4194304 + (long)h * 262144;
    const long n0 = (long)blockIdx.x * 128;
    const int tid = threadIdx.x;
    const int lane = tid & 63, w = tid >> 6;
    const int wm = (w >> 1) * 64, wn = (w & 1) * 64;
    const int lrow = lane & 15, quad = lane >> 4;

    floatx4 acc[4][4] = {};

    for (int k0 = 0; k0 < 512; k0 += 64) {
        __syncthreads();
        #pragma unroll
        for (int t = 0; t < 4; ++t) {
            const int c = t * 256 + tid;
            const int r = c >> 3, kc = (c & 7) * 8;
            __builtin_amdgcn_global_load_lds(
                (const __attribute__((address_space(1))) unsigned int*)(Ab + (long)r * 512 + k0 + kc),
                (__attribute__((address_space(3))) unsigned int*)(As + (long)c * 8), 16, 0, 0);
            __builtin_amdgcn_global_load_lds(
                (const __attribute__((address_space(1))) unsigned int*)(Bb + (n0 + r) * 512 + k0 + kc),
                (__attribute__((address_space(3))) unsigned int*)(Bs + (long)c * 8), 16, 0, 0);
        }
        __syncthreads();
        #pragma unroll
        for (int kk = 0; kk < 64; kk += 32) {
            bf16x8 af[4], bv[4];
            #pragma unroll
            for (int i = 0; i < 4; ++i) {
                af[i] = ldb8(&As[(wm + i * 16 + lrow) * 64 + kk + quad * 8]);
                bv[i] = ldb8(&Bs[(wn + i * 16 + lrow) * 64 + kk + quad * 8]);
            }
            #pragma unroll
            for (int i = 0; i < 4; ++i)
                #pragma unroll
                for (int j = 0; j < 4; ++j)
                    acc[i][j] = MFMA(af[i], bv[j], acc[i][j]);
        }
    }
    #pragma unroll
    for (int mt = 0; mt < 4; ++mt)
        #pragma unroll
        for (int nt = 0; nt < 4; ++nt)
            #pragma unroll
            for (int r = 0; r < 4; ++r)
                Cb[(long)(wm + mt * 16 + quad * 4 + r) * 2048 + n0 + wn + nt * 16 + lrow] = f2bf(acc[mt][nt][r]);
}

// ---------------------------------------------------------------- RMSNorm over cols [0,1536) of 2176-stride rows (in-place)
__global__ __launch_bounds__(256) void rms1536(
    ushort* qk, const float* __restrict__ w) {
    const int row = blockIdx.x, t = threadIdx.x;
    const int lane = t & 63, wv = t >> 6;
    ushort* ip = qk + (long)row * 2176;
    float v[6]; float ss = 0.f;
    #pragma unroll
    for (int i = 0; i < 6; ++i) { v[i] = bf2f(ip[i * 256 + t]); ss += v[i] * v[i]; }
    #pragma unroll
    for (int off = 32; off > 0; off >>= 1) ss += __shfl_xor(ss, off);
    __shared__ float red[4];
    if (lane == 0) red[wv] = ss;
    __syncthreads();
    const float tot = red[0] + red[1] + red[2] + red[3];
    const float sc = rsqrtf(tot * (1.f / 1536.f) + 1e-6f);
    #pragma unroll
    for (int i = 0; i < 6; ++i) ip[i * 256 + t] = f2bf(v[i] * sc * w[i * 256 + t]);
}

// ---------------------------------------------------------------- q RoPE (table-driven)
__global__ __launch_bounds__(256) void qrope(
    const ushort* __restrict__ q, const float2* __restrict__ trig,
    ushort* __restrict__ qpe) {
    const int tok = blockIdx.x;
    const int s = tok & 2047;
    const int t = threadIdx.x;
    #pragma unroll
    for (int p = 0; p < 2; ++p) {
        const int idx = p * 256 + t;
        const int h = idx >> 5, i = idx & 31;
        const long base = (long)tok * 3072 + h * 192 + 128 + 2 * i;
        float x0 = bf2f(q[base]), x1 = bf2f(q[base + 1]);
        float2 cs = trig[s * 32 + i];
        const long ob = (long)tok * 1024 + h * 64 + 2 * i;
        qpe[ob]     = f2bf(x0 * cs.x - x1 * cs.y);
        qpe[ob + 1] = f2bf(x0 * cs.y + x1 * cs.x);
    }
}

// ---------------------------------------------------------------- kv prep: rmsnorm latent + k rope, from qk_comb cols [1536,2112)
__global__ __launch_bounds__(256) void kvprep(
    const ushort* __restrict__ qk, const float* __restrict__ w,
    const float2* __restrict__ trig, ushort* __restrict__ kvc,
    ushort* __restrict__ kpe) {
    const int tok = blockIdx.x;
    const int s = tok & 2047;
    const int t = threadIdx.x;
    const int lane = t & 63, wv = t >> 6;
    const ushort* in2 = qk + (long)tok * 2176 + 1536;
    const float v0 = bf2f(in2[t]);
    const float v1 = bf2f(in2[256 + t]);
    float ss = v0 * v0 + v1 * v1;
    #pragma unroll
    for (int off = 32; off > 0; off >>= 1) ss += __shfl_xor(ss, off);
    __shared__ float red[4];
    if (lane == 0) red[wv] = ss;
    __syncthreads();
    const float tot = red[0] + red[1] + red[2] + red[3];
    const float sc = rsqrtf(tot * (1.f / 512.f) + 1e-6f);
    kvc[(long)tok * 512 + t] = f2bf(v0 * sc * w[t]);
    kvc[(long)tok * 512 + 256 + t] = f2bf(v1 * sc * w[256 + t]);
    if (t < 32) {
        float x0 = bf2f(in2[512 + 2 * t]);
        float x1 = bf2f(in2[512 + 2 * t + 1]);
        float2 cs = trig[s * 32 + t];
        kpe[(long)tok * 64 + 2 * t]     = f2bf(x0 * cs.x - x1 * cs.y);
        kpe[(long)tok * 64 + 2 * t + 1] = f2bf(x0 * cs.y + x1 * cs.x);
    }
}

// ---------------------------------------------------------------- flash attention, non-absorbed (per-head MHA)
// r8 banked structure (110 us) + T13 defer-max (THR = 8 nats = 11.5417 log2-units):
// keep old running max while growth <= THR -> alpha == 1.0 exactly -> rescale skipped.
// P bounded by 2^11.54 (bf16 relative precision is magnitude-independent -> exact-identity
// algebra, no extra rounding error class). T14 removed (r9: clean null).
// D_QK = 192 (128 nope + 64 rope in Ks), D_V = 128. Q-tile 64, KV-tile 128.
// Grid (16,16,2); block handles q-tiles {qx, 31-qx} -> 17 kv-iters (perfect balance).
// XCD remap keeps each (b,h) group on one XCD (kn+vT slice L2-resident).
__global__ __launch_bounds__(256, 2) void mha_attn(
    const ushort* __restrict__ q,      // (4096,3072): per-head 192, [0,128) nope
    const ushort* __restrict__ qpe,    // (4096,16,64) roped
    const ushort* __restrict__ kn,     // (2,2048,2048): k_nope, col h*128+d
    const ushort* __restrict__ kpe,    // (4096,64) roped, shared across heads
    const ushort* __restrict__ vT,     // (2,16,128,2048)
    ushort* __restrict__ o2) {         // (4096,2048): col h*128+d
    __shared__ __align__(16) ushort Ks[128][200];   // cols 0-127 nope, 128-191 rope
    __shared__ __align__(16) ushort P[64][136];     // cols 128-129 alpha(f32), 132-133 l(f32)
    // ---- XCD-aware bijective remap of (qx, h, b) ----
    const int fid = blockIdx.x + (blockIdx.y << 4) + (blockIdx.z << 8);  // 0..511
    const int xcd = fid & 7, j = fid >> 3;          // 64 blocks per XCD chunk
    const int g = xcd * 4 + (j >> 4);               // (b,h) group 0..31
    const int qx = j & 15, h = g & 15, b = g >> 4;
    const int tid = threadIdx.x, lane = tid & 63, w = tid >> 6;
    const int lrow = lane & 15, quad = lane >> 4;
    const long bb = (long)b * 2048;
    const float scale = 0.07216878364870323f * 1.4426950408889634f;  // 192^-0.5 * log2(e)
    const float THR = 11.5417f;                      // 8 nats in log2 units (HK THR=8)
    const int rn = tid >> 4, cn = (tid & 15) * 8;   // nope staging: 16 lanes/row (256B rows)
    const int rr = tid >> 3, cr = (tid & 7) * 8;    // rope staging: 8 lanes/row (128B rows)

    for (int half = 0; half < 2; ++half) {
        const int qt = half ? (31 - qx) : qx;
        const int qrow = qt * 64;
        const long tokb = bb + qrow;

        bf16x8 qa[6];
        {
            const ushort* qp_ = q + (tokb + w * 16 + lrow) * 3072 + h * 192 + quad * 8;
            #pragma unroll
            for (int ks = 0; ks < 4; ++ks) qa[ks] = ldb8(qp_ + ks * 32);
            const ushort* qq = qpe + (tokb + w * 16 + lrow) * 1024 + h * 64 + quad * 8;
            qa[4] = ldb8(qq); qa[5] = ldb8(qq + 32);
        }

        floatx4 oacc[4][2] = {};     // [m-frag][v-frag]; wave owns v-dims [w*32, w*32+32)
        float m_i[4], l_i[4];
        #pragma unroll
        for (int r = 0; r < 4; ++r) { m_i[r] = -1e30f; l_i[r] = 0.f; }

        const int niter = qt / 2 + 1;
        for (int t = 0; t < niter; ++t) {
            const int kv0 = t * 128;
            // ---- stage K-tile (128 kv x (128 nope + 64 rope)) into LDS ----
            {
                const ushort* src = kn + (bb + kv0 + rn) * 2048 + h * 128 + cn;
                #pragma unroll
                for (int j2 = 0; j2 < 8; ++j2) {
                    uint4 v = *(const uint4*)(src + (long)j2 * 16 * 2048);
                    *(uint4*)&Ks[j2 * 16 + rn][cn] = v;
                }
                const ushort* srp = kpe + (bb + kv0 + rr) * 64 + cr;
                #pragma unroll
                for (int j2 = 0; j2 < 4; ++j2) {
                    uint4 v = *(const uint4*)(srp + (long)j2 * 32 * 64);
                    *(uint4*)&Ks[j2 * 32 + rr][128 + cr] = v;
                }
            }
            __syncthreads();  // A: stage visible; prev-iter P reads done

            // ---- QK^T: wave w owns q-rows [w*16, w*16+16), all 128 kv cols ----
            floatx4 sacc[8] = {};
            __builtin_amdgcn_s_setprio(1);
            #pragma unroll
            for (int f = 0; f < 8; ++f)
                #pragma unroll
                for (int ks = 0; ks < 6; ++ks)
                    sacc[f] = MFMA(qa[ks], ldb8(&Ks[f * 16 + lrow][ks * 32 + quad * 8]), sacc[f]);
            __builtin_amdgcn_s_setprio(0);

            // ---- prefetch V b-frags (L2-resident after remap) ----
            bf16x8 vf[2][4];
            {
                const ushort* vb = vT + ((long)(b * 16 + h)) * 262144 + (long)(w * 32 + lrow) * 2048 + kv0 + quad * 8;
                #pragma unroll
                for (int nf = 0; nf < 2; ++nf)
                    #pragma unroll
                    for (int kk = 0; kk < 4; ++kk)
                        vf[nf][kk] = ldb8(vb + (long)nf * 16 * 2048 + kk * 32);
            }

            // ---- online softmax (log2 domain, defer-max) over 128 kv cols ----
            const bool diag = (t == niter - 1);
            #pragma unroll
            for (int r = 0; r < 4; ++r) {
                const int rloc = w * 16 + quad * 4 + r;
                const int row_s = qrow + rloc;
                float pv[8];
                float smax = -1e30f;
                #pragma unroll
                for (int f = 0; f < 8; ++f) {
                    pv[f] = sacc[f][r] * scale;
                    if (diag) { if (kv0 + f * 16 + lrow > row_s) pv[f] = -1e30f; }
                    smax = fmaxf(smax, pv[f]);
                }
                #pragma unroll
                for (int off = 1; off < 16; off <<= 1)
                    smax = fmaxf(smax, __shfl_xor(smax, off));
                // T13: keep old max unless growth exceeds THR -> alpha == 1.0 exactly
                const float mnew = (smax > m_i[r] + THR) ? smax : m_i[r];
                const float alpha = __builtin_amdgcn_exp2f(m_i[r] - mnew);
                float ps = 0.f;
                #pragma unroll
                for (int f = 0; f < 8; ++f) {
                    float p = __builtin_amdgcn_exp2f(pv[f] - mnew);
                    P[rloc][f * 16 + lrow] = f2bf_n(p);
                    ps += p;
                }
                #pragma unroll
                for (int off = 1; off < 16; off <<= 1)
                    ps += __shfl_xor(ps, off);
                l_i[r] = l_i[r] * alpha + ps;
                m_i[r] = mnew;
                if (lrow == 0) *(float*)&P[rloc][128] = alpha;
            }
            __syncthreads();  // B: P + alpha visible

            // ---- PV: wave w owns v-dims [w*32, +32), all 64 q-rows ----
            __builtin_amdgcn_s_setprio(1);
            #pragma unroll
            for (int mf = 0; mf < 4; ++mf) {
                float al[4];
                #pragma unroll
                for (int r = 0; r < 4; ++r) al[r] = *(const float*)&P[mf * 16 + quad * 4 + r][128];
                const int need = (al[0] != 1.f) | (al[1] != 1.f) | (al[2] != 1.f) | (al[3] != 1.f);
                if (__any(need)) {
                    #pragma unroll
                    for (int nf = 0; nf < 2; ++nf)
                        #pragma unroll
                        for (int r = 0; r < 4; ++r) oacc[mf][nf][r] *= al[r];
                }
                #pragma unroll
                for (int kk = 0; kk < 4; ++kk) {
                    bf16x8 pf = ldb8(&P[mf * 16 + lrow][kk * 32 + quad * 8]);
                    oacc[mf][0] = MFMA(pf, vf[0][kk], oacc[mf][0]);
                    oacc[mf][1] = MFMA(pf, vf[1][kk], oacc[mf][1]);
                }
            }
            __builtin_amdgcn_s_setprio(0);
        }

        // ---- epilogue ----
        #pragma unroll
        for (int r = 0; r < 4; ++r)
            if (lrow == 0) *(float*)&P[w * 16 + quad * 4 + r][132] = l_i[r];
        __syncthreads();
        #pragma unroll
        for (int mf = 0; mf < 4; ++mf) {
            float li[4];
            #pragma unroll
            for (int r = 0; r < 4; ++r) li[r] = *(const float*)&P[mf * 16 + quad * 4 + r][132];
            #pragma unroll
            for (int nf = 0; nf < 2; ++nf)
                #pragma unroll
                for (int r = 0; r < 4; ++r) {
                    long tok = tokb + mf * 16 + quad * 4 + r;
                    o2[tok * 2048 + h * 128 + w * 32 + nf * 16 + lrow] = f2bf_n(oacc[mf][nf][r] / li[r]);
                }
        }
        __syncthreads();  // protect P/Ks before next half
    }
}

// ---------------------------------------------------------------- launcher
extern "C" void kernel_launch(void* const* d_in, const int* in_sizes, int n_in,
                              void* d_out, int out_size, void* d_ws, size_t ws_size,
                              hipStream_t stream) {
    const float* x      = (const float*)d_in[0];
    const float* freqs  = (const float*)d_in[1];
    const float* wq_a   = (const float*)d_in[3];
    const float* qnw    = (const float*)d_in[4];
    const float* wq_b   = (const float*)d_in[5];
    const float* wkv_a  = (const float*)d_in[6];
    const float* kvnw   = (const float*)d_in[7];
    const float* wkv_b  = (const float*)d_in[8];
    const float* wo     = (const float*)d_in[9];
    float* out = (float*)d_out;
    (void)ws_size; (void)in_sizes; (void)n_in; (void)out_size;

    char* ws = (char*)d_ws;
    // lifetimes: qk_comb dies after kvprep -> o2 overlays it.
    //            xb dies after combined GEMM -> knope overlays it.
    ushort* qk_comb = (ushort*)(ws + 0);            // 4096x2176 bf16 = 17,825,792
    ushort* o2      = (ushort*)(ws + 0);            // 16,777,216 (after kvprep)
    ushort* xb      = (ushort*)(ws + 17825792);     // 16,777,216
    ushort* knope   = (ushort*)(ws + 17825792);     // 16,777,216 (after comb GEMM)
    ushort* q       = (ushort*)(ws + 34603008);     // 25,165,824
    ushort* qpe     = (ushort*)(ws + 59768832);     // 8,388,608
    ushort* kvc     = (ushort*)(ws + 68157440);     // 4,194,304
    ushort* kpe     = (ushort*)(ws + 72351744);     // 524,288
    ushort* vT      = (ushort*)(ws + 72876032);     // 16,777,216
    ushort* wcombT  = (ushort*)(ws + 89653248);     // 2176x2048 bf16 = 8,912,896
    ushort* wq_bT   = (ushort*)(ws + 98566144);     // 9,437,184
    ushort* wkv_bT  = (ushort*)(ws + 108003328);    // 4,194,304
    ushort* woT     = (ushort*)(ws + 112197632);    // 8,388,608
    float2* trig    = (float2*)(ws + 120586240);    // 524,288 -> ends 121,110,528

    dim3 tb(32, 8);
    trigtab<<<256, 256, 0, stream>>>(freqs, trig);
    // concat transposed weights: rows 0-1535 = wq_a^T, rows 1536-2111 = wkv_a^T, 2112-2175 pad
    transpose_f32_bf16<<<dim3(48, 64), tb, 0, stream>>>(wq_a, wcombT, 2048, 1536);
    transpose_f32_bf16<<<dim3(18, 64), tb, 0, stream>>>(wkv_a, wcombT + 1536L * 2048, 2048, 576);
    transpose_f32_bf16<<<dim3(96, 48), tb, 0, stream>>>(wq_b, wq_bT, 1536, 3072);
    transpose_f32_bf16<<<dim3(128, 16), tb, 0, stream>>>(wkv_b, wkv_bT, 512, 4096);
    transpose_f32_bf16<<<dim3(64, 64), tb, 0, stream>>>(wo, woT, 2048, 2048);
    cvt_f32_bf16<<<8192, 256, 0, stream>>>(x, xb, 8388608L);

    // qk_comb = x @ [wq_a | wkv_a]   (4096 x 2176, K=2048; cols 2112+ junk)
    gemm_bt128<<<dim3(17, 32, 1), 256, 0, stream>>>(xb, wcombT, qk_comb, 2048, 2048, 2048, 2176, 0, 0, 0, 0);
    // rmsnorm cols [0,1536) in place
    rms1536<<<4096, 256, 0, stream>>>(qk_comb, qnw);
    // q = qn @ wq_b               (4096 x 3072, K=1536; A stride 2176)
    gemm_bt128<<<dim3(24, 32, 1), 256, 0, stream>>>(qk_comb, wq_bT, q, 1536, 2176, 1536, 3072, 0, 0, 0, 0);
    // q_pe = rope(q[..., 128:192])
    qrope<<<4096, 256, 0, stream>>>(q, trig, qpe);
    // kvc (rmsnormed latent) / kpe  from qk_comb cols [1536,2112)
    kvprep<<<4096, 256, 0, stream>>>(qk_comb, kvnw, trig, kvc, kpe);

    // k_nope[b,s,h*128+d] = sum_c kvc[b,s,c] * wkv_b[c, h*256+d]   (z = head, both batches)
    gemm_bt128<<<dim3(1, 32, 16), 256, 0, stream>>>(kvc, wkv_bT, knope,
        512, 512, 512, 2048, 0, 131072, 128, 0);
    // vT for both batches in ONE launch (z = b*16+h)
    gemm_vt<<<dim3(16, 1, 32), 256, 0, stream>>>(wkv_bT + 65536, kvc, vT);

    // flash attention (non-absorbed), writes per-head O directly
    mha_attn<<<dim3(16, 16, 2), 256, 0, stream>>>(q, qpe, knope, kpe, vT, o2);

    // out = o2 @ wo (fp32 output)
    gemm_bt128<<<dim3(16, 32, 1), 256, 0, stream>>>(o2, woT, out, 2048, 2048, 2048, 2048, 0, 0, 0, 1);
}